// Round 1
// baseline (14265.155 us; speedup 1.0000x reference)
//
#include <hip/hip_runtime.h>

#define B_ 16
#define T_ 2048
#define L_ 512
#define HD 200
#define AT 50

__device__ __forceinline__ float rcp_(float x){ return __builtin_amdgcn_rcpf(x); }
__device__ __forceinline__ float sigf(float x){ return rcp_(1.f + __expf(-x)); }
__device__ __forceinline__ float tanhf_(float x){
  x = fminf(15.f, fmaxf(-15.f, x));
  float e = __expf(-2.f*x);
  return (1.f - e) * rcp_(1.f + e);
}

// ---------------- conv fold: E[3][256] ----------------
__global__ void k_prep(const float* __restrict__ conv1, const float* __restrict__ conv1a,
                       const float* __restrict__ conv2, const float* __restrict__ conv3,
                       float* __restrict__ E)
{
  __shared__ float K2s[3*256];
  int tid = threadIdx.x;            // 768 threads
  int k = tid >> 8, co = tid & 255;
  float a = 0.f;
  for (int ci = 0; ci < 256; ++ci)
    a = fmaf(conv1[ci], conv2[(k*256 + ci)*256 + co], a);
  K2s[k*256 + co] = a;
  __syncthreads();
  float b2 = 0.f;
  for (int ci = 0; ci < 256; ++ci)
    b2 = fmaf(K2s[k*256 + ci], conv3[ci*256 + co], b2);
  if (k == 1) b2 += conv1a[co];
  E[k*256 + co] = b2;
}

// ---------------- feat[b,t,256] ----------------
__global__ void k_feat(const float* __restrict__ sig, const float* __restrict__ E,
                       const float* __restrict__ c1ab, float* __restrict__ feat)
{
  int idx = blockIdx.x*256 + threadIdx.x;   // grid 8192 -> 32768*64 float4
  int row = idx >> 6;
  int c4  = (idx & 63) * 4;
  int t = row & (T_-1);
  float sm = (t > 0)     ? sig[row-1] : 0.f;
  float s0 = sig[row];
  float sp = (t < T_-1)  ? sig[row+1] : 0.f;
  float4 e0 = *(const float4*)&E[0*256 + c4];
  float4 e1 = *(const float4*)&E[1*256 + c4];
  float4 e2 = *(const float4*)&E[2*256 + c4];
  float4 bb = *(const float4*)&c1ab[c4];
  float4 r;
  r.x = fmaxf(0.f, fmaf(sm, e0.x, fmaf(s0, e1.x, fmaf(sp, e2.x, bb.x))));
  r.y = fmaxf(0.f, fmaf(sm, e0.y, fmaf(s0, e1.y, fmaf(sp, e2.y, bb.y))));
  r.z = fmaxf(0.f, fmaf(sm, e0.z, fmaf(s0, e1.z, fmaf(sp, e2.z, bb.z))));
  r.w = fmaxf(0.f, fmaf(sm, e0.w, fmaf(s0, e1.w, fmaf(sp, e2.w, bb.w))));
  *(float4*)&feat[(size_t)row*256 + c4] = r;
}

// ---------------- generic fp32 GEMM: C[M,N] = A[M,K]*B[K,N] (+bias) ----------------
__global__ __launch_bounds__(256)
void k_gemm(const float* __restrict__ A, const float* __restrict__ B,
            const float* __restrict__ bias, float* __restrict__ C,
            int M, int N, int K, int ldb)
{
  __shared__ float As[16][65];
  __shared__ float Bs[16][65];
  int row0 = blockIdx.x*64, col0 = blockIdx.y*64;
  int tid = threadIdx.x;
  int tm = tid >> 4, tn = tid & 15;
  float acc[4][4] = {};
  for (int k0 = 0; k0 < K; k0 += 16){
    #pragma unroll
    for (int i = 0; i < 4; ++i){
      int e = tid + i*256;
      int m = e >> 4, kk = e & 15;
      float v = 0.f;
      if (k0 + kk < K) v = A[(size_t)(row0+m)*K + k0 + kk];
      As[kk][m] = v;
      int n = e & 63, kb = e >> 6;
      float w = 0.f;
      if (k0 + kb < K && col0 + n < N) w = B[(size_t)(k0+kb)*ldb + col0 + n];
      Bs[kb][n] = w;
    }
    __syncthreads();
    #pragma unroll
    for (int kk = 0; kk < 16; ++kk){
      float a[4], bv[4];
      #pragma unroll
      for (int i = 0; i < 4; ++i){ a[i] = As[kk][tm*4+i]; bv[i] = Bs[kk][tn*4+i]; }
      #pragma unroll
      for (int i = 0; i < 4; ++i)
        #pragma unroll
        for (int j = 0; j < 4; ++j)
          acc[i][j] = fmaf(a[i], bv[j], acc[i][j]);
    }
    __syncthreads();
  }
  #pragma unroll
  for (int i = 0; i < 4; ++i){
    int r = row0 + tm*4 + i;
    #pragma unroll
    for (int j = 0; j < 4; ++j){
      int cc = col0 + tn*4 + j;
      if (cc < N) C[(size_t)r*N + cc] = acc[i][j] + (bias ? bias[cc] : 0.f);
    }
  }
}

// ---------------- encoder: one block per (dir,b) chain ----------------
__global__ __launch_bounds__(512, 2)
void k_encoder(const float* __restrict__ xprojF, const float* __restrict__ xprojB,
               const float* __restrict__ W_fwd, const float* __restrict__ W_bwd,
               const int* __restrict__ sig_len, float* __restrict__ memory,
               float* __restrict__ c0h0, int dirParam)
{
  int dir, b;
  if (dirParam < 0){ dir = blockIdx.x & 1; b = blockIdx.x >> 1; }
  else             { dir = dirParam;       b = blockIdx.x; }
  const float* xp = dir ? xprojB : xprojF;
  const float* W  = dir ? W_bwd  : W_fwd;
  int tid = threadIdx.x;
  __shared__ __align__(16) float h_lds[100];
  __shared__ float z_lds[400];
  float U[100];
  if (tid < 400){
    #pragma unroll
    for (int j = 0; j < 100; ++j) U[j] = W[(256 + j)*400 + tid];
  }
  if (tid < 100) h_lds[tid] = 0.f;
  float c = 0.f, hfin = 0.f;
  int len = sig_len[b];
  // prefetch first xproj value
  float xnext = 0.f;
  {
    int t0 = dir ? (len - 1) : 0;
    if (tid < 400) xnext = xp[(size_t)(b*T_ + t0)*400 + tid];
  }
  for (int step = 0; step < len; ++step){
    int t = dir ? (len - 1 - step) : step;
    __syncthreads();            // h ready
    float z = 0.f;
    if (tid < 400){
      float acc0 = xnext, acc1 = 0.f, acc2 = 0.f, acc3 = 0.f;
      #pragma unroll
      for (int j4 = 0; j4 < 25; ++j4){
        float4 h4 = *(const float4*)&h_lds[j4*4];
        acc0 = fmaf(h4.x, U[j4*4+0], acc0);
        acc1 = fmaf(h4.y, U[j4*4+1], acc1);
        acc2 = fmaf(h4.z, U[j4*4+2], acc2);
        acc3 = fmaf(h4.w, U[j4*4+3], acc3);
      }
      z = (acc0 + acc1) + (acc2 + acc3);
      z_lds[tid] = z;
      if (step + 1 < len){
        int tn = dir ? (t - 1) : (t + 1);
        xnext = xp[(size_t)(b*T_ + tn)*400 + tid];
      }
    }
    __syncthreads();
    if (tid < 100){
      float zi = z_lds[tid], zj = z_lds[tid+100], zf = z_lds[tid+200], zo = z_lds[tid+300];
      c = c * sigf(zf + 1.0f) + sigf(zi) * tanhf_(zj);
      float nh = tanhf_(c) * sigf(zo);
      hfin = nh;
      h_lds[tid] = nh;          // safe: all reads done before 2nd barrier
      memory[(size_t)(b*T_ + t)*200 + dir*100 + tid] = nh;
    }
  }
  if (tid < 100){
    c0h0[b*400 + dir*100 + tid]       = c;
    c0h0[b*400 + 200 + dir*100 + tid] = hfin;
  }
  // zero output tail (dynamic_rnn zeroes outputs past length)
  int total = (T_ - len) * 100;
  for (int i = tid; i < total; i += 512){
    int t = len + i/100;
    int k = i - (i/100)*100;
    memory[(size_t)(b*T_ + t)*200 + dir*100 + k] = 0.f;
  }
}

// ---------------- decoder input gather ----------------
__global__ void k_gather(const float* __restrict__ emb, const int* __restrict__ labels,
                         float* __restrict__ dA)
{
  int idx = blockIdx.x*256 + threadIdx.x;  // grid 2048 -> 8192*64
  int i = idx >> 6, e = idx & 63;
  dA[(size_t)i*64 + e] = emb[labels[i]*64 + e];
}

// ---------------- decoder init: zero out, init nhbuf/ctrs ----------------
__global__ void k_dec_init(const float* __restrict__ c0h0, float* __restrict__ nhbuf,
                           unsigned int* __restrict__ ctrs, float* __restrict__ out)
{
  int idx = blockIdx.x*256 + threadIdx.x;   // grid 64
  for (int i = idx; i < B_*L_*6; i += 64*256) out[i] = 0.f;
  for (int i = idx; i < B_*HD; i += 64*256){
    int b = i / HD, d = i - (i/HD)*HD;
    nhbuf[(0*B_ + b)*HD + d]  = c0h0[b*400 + 200 + d];
    nhbuf[(B_ + b)*HD + d]    = 0.f;
  }
  if (idx < 32) ctrs[idx] = 0u;
}

// ---------------- cooperative decoder: 16 blocks per batch item ----------------
#define DEC_LDS 138240
#define TCH 128

__global__ __launch_bounds__(256, 1)
void k_decoder(const float* __restrict__ keysG, const float* __restrict__ memAG,
               const float* __restrict__ decx,  const float* __restrict__ W_dec,
               const float* __restrict__ W_attn, const float* __restrict__ W_out,
               const float* __restrict__ c0h0, const int* __restrict__ sig_len,
               const int* __restrict__ base_len,
               float* nhbuf, float* partials, unsigned int* ctrs,
               float* __restrict__ out)
{
  int blk = blockIdx.x;
  int b = blk >> 4;
  int g = blk & 15;
  int tid = threadIdx.x;
  int u0 = g * 13;
  int nu = (HD - u0 < 13) ? (HD - u0) : 13;   // 13 for g<15, 5 for g==15
  if (nu < 0) nu = 0;
  int t0 = g * TCH;

  extern __shared__ char smem[];
  unsigned short* keyL = (unsigned short*)(smem);          // [128][200] bf16
  float* memAL = (float*)(smem + 51200);                   // [128][50]
  float* Uld   = (float*)(smem + 76800);                   // [250][52]
  float* Wa1s  = (float*)(smem + 128800);                  // [13][50]
  float* WoutL = (float*)(smem + 131400);                  // [50][6]
  float* xv    = (float*)(smem + 132600);                  // [250]
  float* zp    = (float*)(smem + 133600);                  // [52][4]
  float* zfu   = (float*)(smem + 134432);                  // [52]
  float* nhF   = (float*)(smem + 134640);                  // [200] (16B aligned)
  float* wL    = (float*)(smem + 135440);                  // [128]
  float* spL   = (float*)(smem + 135952);                  // [256]
  float* cpL   = (float*)(smem + 136976);                  // [4][52]
  float* cL    = (float*)(smem + 137808);                  // [13]
  float* attnL = (float*)(smem + 137872);                  // [50]
  float* SL    = (float*)(smem + 138072);                  // [1]

  // ---- one-time loads
  for (int i = tid; i < TCH*200; i += 256){
    int t = i / 200, d = i - (i/200)*200;
    float v = keysG[((size_t)b*T_ + t0 + t)*200 + d];
    unsigned u = __float_as_uint(v);
    u += 0x7FFFu + ((u >> 16) & 1u);          // rne to bf16
    keyL[i] = (unsigned short)(u >> 16);
  }
  for (int i = tid; i < TCH*AT; i += 256){
    int t = i / AT, d = i - (i/AT)*AT;
    memAL[i] = memAG[((size_t)b*T_ + t0 + t)*AT + d];
  }
  for (int i = tid; i < 250*52; i += 256){
    int j = i / 52, o = i - (i/52)*52;
    int u = o >> 2, gg = o & 3;
    Uld[i] = (u < nu) ? W_dec[(size_t)(64 + j)*800 + gg*200 + u0 + u] : 0.f;
  }
  for (int i = tid; i < 13*AT; i += 256){
    int u = i / AT, d = i - (i/AT)*AT;
    Wa1s[i] = (u < nu) ? W_attn[(size_t)(u0 + u)*AT + d] : 0.f;
  }
  for (int i = tid; i < 300; i += 256) WoutL[i] = W_out[i];
  if (tid < nu) cL[tid] = c0h0[b*400 + u0 + tid];
  if (tid < AT) attnL[tid] = 0.f;
  int len = sig_len[b];
  int Lb  = base_len[b];
  unsigned int* ctr = ctrs + b*2;
  __syncthreads();

  for (int l = 0; l < Lb; ++l){
    // prefetch decx for this step (consumed after zp barrier)
    float dcx = 0.f;
    if (tid < 4*nu){
      int u = tid >> 2, gg = tid & 3;
      dcx = decx[((size_t)b*L_ + l)*800 + gg*200 + u0 + u];
    }
    // ---- P1: build x = [attn(50), h(200)]
    if (tid < AT) xv[tid] = attnL[tid];
    else if (tid < 250)
      xv[tid] = __hip_atomic_load(&nhbuf[((l & 1)*B_ + b)*HD + (tid - AT)],
                                  __ATOMIC_RELAXED, __HIP_MEMORY_SCOPE_AGENT);
    __syncthreads();
    // gemv partials over j
    if (tid < 208){
      int jc = tid / 52;
      int o  = tid - jc*52;
      int jlo = (jc < 2) ? jc*63 : 126 + (jc - 2)*62;
      int jhi = jlo + ((jc < 2) ? 63 : 62);
      float a = 0.f;
      for (int j = jlo; j < jhi; ++j)
        a = fmaf(xv[j], Uld[j*52 + o], a);
      zp[o*4 + jc] = a;
    }
    __syncthreads();
    if (tid < 4*nu){
      zfu[tid] = zp[tid*4+0] + zp[tid*4+1] + zp[tid*4+2] + zp[tid*4+3] + dcx;
    }
    __syncthreads();
    if (tid < nu){
      float zi = zfu[tid*4+0], zj = zfu[tid*4+1], zf = zfu[tid*4+2], zo = zfu[tid*4+3];
      float c = cL[tid];
      c = c * sigf(zf + 1.0f) + sigf(zi) * tanhf_(zj);
      cL[tid] = c;
      float nh = tanhf_(c) * sigf(zo);
      __hip_atomic_store(&nhbuf[(((l+1) & 1)*B_ + b)*HD + u0 + tid], nh,
                         __ATOMIC_RELAXED, __HIP_MEMORY_SCOPE_AGENT);
    }
    __syncthreads();
    // ---- barrier A (nh ready across the 16 blocks of this b)
    if (tid == 0){
      __hip_atomic_fetch_add(&ctr[0], 1u, __ATOMIC_ACQ_REL, __HIP_MEMORY_SCOPE_AGENT);
      unsigned tgt = 16u * (unsigned)(l + 1);
      while (__hip_atomic_load(&ctr[0], __ATOMIC_ACQUIRE, __HIP_MEMORY_SCOPE_AGENT) < tgt)
        __builtin_amdgcn_s_sleep(1);
    }
    __syncthreads();
    if (tid < HD)
      nhF[tid] = __hip_atomic_load(&nhbuf[(((l+1) & 1)*B_ + b)*HD + tid],
                                   __ATOMIC_RELAXED, __HIP_MEMORY_SCOPE_AGENT);
    __syncthreads();
    // ---- P3: scores over this block's t-chunk (bf16 keys)
    {
      int t = tid >> 1, half = tid & 1;
      const unsigned* kp = (const unsigned*)keyL + t*100 + half*50;
      const float4* nh4 = (const float4*)(nhF + half*100);
      float s0 = 0.f, s1 = 0.f;
      #pragma unroll
      for (int q2 = 0; q2 < 25; ++q2){
        float4 nv = nh4[q2];
        unsigned ua = kp[2*q2], ub = kp[2*q2+1];
        s0 = fmaf(nv.x, __uint_as_float(ua << 16), s0);
        s1 = fmaf(nv.y, __uint_as_float(ua & 0xFFFF0000u), s1);
        s0 = fmaf(nv.z, __uint_as_float(ub << 16), s0);
        s1 = fmaf(nv.w, __uint_as_float(ub & 0xFFFF0000u), s1);
      }
      spL[tid] = s0 + s1;
    }
    __syncthreads();
    if (tid < TCH){
      float s = spL[tid*2] + spL[tid*2+1];
      int tg = t0 + tid;
      float w = 0.f;
      if (tg < len){
        s = fminf(60.f, fmaxf(-60.f, s));
        w = __expf(s);
      }
      wL[tid] = w;
    }
    __syncthreads();
    if (tid < 64){
      float v = wL[tid] + wL[tid + 64];
      #pragma unroll
      for (int off = 32; off > 0; off >>= 1) v += __shfl_down(v, off);
      if (tid == 0) SL[0] = v;
    }
    {
      int d = tid & 63, tc = tid >> 6;
      if (d < AT){
        float a = 0.f;
        for (int t = tc*32; t < tc*32 + 32; ++t)
          a = fmaf(wL[t], memAL[t*AT + d], a);
        cpL[tc*52 + d] = a;
      }
    }
    __syncthreads();
    if (tid < AT){
      float ctx = cpL[0*52+tid] + cpL[1*52+tid] + cpL[2*52+tid] + cpL[3*52+tid];
      float ap = 0.f;
      for (int u = 0; u < nu; ++u)
        ap = fmaf(nhF[u0 + u], Wa1s[u*AT + tid], ap);
      float* pb = partials + ((size_t)b*16 + g)*104;
      __hip_atomic_store(&pb[tid],      ctx, __ATOMIC_RELAXED, __HIP_MEMORY_SCOPE_AGENT);
      __hip_atomic_store(&pb[50 + tid], ap,  __ATOMIC_RELAXED, __HIP_MEMORY_SCOPE_AGENT);
      if (tid == 0)
        __hip_atomic_store(&pb[100], SL[0], __ATOMIC_RELAXED, __HIP_MEMORY_SCOPE_AGENT);
    }
    __syncthreads();
    // ---- barrier B (partials ready)
    if (tid == 0){
      __hip_atomic_fetch_add(&ctr[1], 1u, __ATOMIC_ACQ_REL, __HIP_MEMORY_SCOPE_AGENT);
      unsigned tgt = 16u * (unsigned)(l + 1);
      while (__hip_atomic_load(&ctr[1], __ATOMIC_ACQUIRE, __HIP_MEMORY_SCOPE_AGENT) < tgt)
        __builtin_amdgcn_s_sleep(1);
    }
    __syncthreads();
    // ---- P4: every block reduces partials -> attn (identical result)
    if (tid < AT){
      float cs = 0.f, as = 0.f, Ss = 0.f;
      for (int gg = 0; gg < 16; ++gg){
        const float* pb = partials + ((size_t)b*16 + gg)*104;
        cs += __hip_atomic_load(&pb[tid],      __ATOMIC_RELAXED, __HIP_MEMORY_SCOPE_AGENT);
        as += __hip_atomic_load(&pb[50 + tid], __ATOMIC_RELAXED, __HIP_MEMORY_SCOPE_AGENT);
        Ss += __hip_atomic_load(&pb[100],      __ATOMIC_RELAXED, __HIP_MEMORY_SCOPE_AGENT);
      }
      attnL[tid] = as + cs / Ss;
    }
    __syncthreads();
    if (g == 0 && tid < 6){
      float o_ = 0.f;
      for (int d = 0; d < AT; ++d)
        o_ = fmaf(attnL[d], WoutL[d*6 + tid], o_);
      out[((size_t)b*L_ + l)*6 + tid] = o_;
    }
  }
}

extern "C" void kernel_launch(void* const* d_in, const int* in_sizes, int n_in,
                              void* d_out, int out_size, void* d_ws, size_t ws_size,
                              hipStream_t stream)
{
  const float* signals   = (const float*)d_in[0];
  const float* embeddings= (const float*)d_in[1];
  const float* conv1_k   = (const float*)d_in[2];
  const float* conv1a_k  = (const float*)d_in[3];
  const float* conv1a_b  = (const float*)d_in[4];
  const float* conv2_k   = (const float*)d_in[5];
  const float* conv3_k   = (const float*)d_in[6];
  const float* W_fwd     = (const float*)d_in[7];
  const float* b_fwd     = (const float*)d_in[8];
  const float* W_bwd     = (const float*)d_in[9];
  const float* b_bwd     = (const float*)d_in[10];
  const float* W_dec     = (const float*)d_in[11];
  const float* b_dec     = (const float*)d_in[12];
  const float* W_mem     = (const float*)d_in[13];
  const float* W_attn    = (const float*)d_in[14];
  const float* W_out     = (const float*)d_in[15];
  const int*   labels    = (const int*)d_in[16];
  const int*   sig_len   = (const int*)d_in[17];
  const int*   base_len  = (const int*)d_in[18];
  float* out = (float*)d_out;
  char* ws = (char*)d_ws;

  const size_t o_E        = 0;
  const size_t o_c0h0     = 4096;
  const size_t o_nhbuf    = 32768;
  const size_t o_partials = 65536;
  const size_t o_ctr      = 524288;
  const size_t o_feat     = 1u << 20;                 // feat 33.5MB; keys overlays (26.2MB)
  const size_t o_mem      = o_feat + 33554432;        // memory 26.2MB
  const size_t o_X1       = o_mem + 26214400;         // 52.4MB (xproj / later memA+decx)
  const size_t o_X2       = o_X1 + 52428800;          // xprojB if ws is big enough

  bool bigws = (ws_size >= o_X2 + 52428800);

  float* E      = (float*)(ws + o_E);
  float* c0h0   = (float*)(ws + o_c0h0);
  float* nhbuf  = (float*)(ws + o_nhbuf);
  float* parts  = (float*)(ws + o_partials);
  unsigned int* ctrs = (unsigned int*)(ws + o_ctr);
  float* feat   = (float*)(ws + o_feat);
  float* keys   = feat;                               // overlay after encoder
  float* memory = (float*)(ws + o_mem);
  float* xprojF = (float*)(ws + o_X1);
  float* xprojB = bigws ? (float*)(ws + o_X2) : xprojF;
  float* memA   = (float*)(ws + o_X1);                // overlay after encoder
  float* decxA  = (float*)(ws + o_X1 + 6553600);
  float* decx   = (float*)(ws + o_X1 + 8650752);

  k_prep<<<1, 768, 0, stream>>>(conv1_k, conv1a_k, conv2_k, conv3_k, E);
  k_feat<<<8192, 256, 0, stream>>>(signals, E, conv1a_b, feat);

  dim3 gx(512, 7);
  if (bigws){
    k_gemm<<<gx, 256, 0, stream>>>(feat, W_fwd, b_fwd, xprojF, 32768, 400, 256, 400);
    k_gemm<<<gx, 256, 0, stream>>>(feat, W_bwd, b_bwd, xprojB, 32768, 400, 256, 400);
    k_encoder<<<32, 512, 0, stream>>>(xprojF, xprojB, W_fwd, W_bwd, sig_len, memory, c0h0, -1);
  } else {
    k_gemm<<<gx, 256, 0, stream>>>(feat, W_fwd, b_fwd, xprojF, 32768, 400, 256, 400);
    k_encoder<<<16, 512, 0, stream>>>(xprojF, xprojF, W_fwd, W_bwd, sig_len, memory, c0h0, 0);
    k_gemm<<<gx, 256, 0, stream>>>(feat, W_bwd, b_bwd, xprojF, 32768, 400, 256, 400);
    k_encoder<<<16, 512, 0, stream>>>(xprojF, xprojF, W_fwd, W_bwd, sig_len, memory, c0h0, 1);
  }

  k_gemm<<<dim3(512, 4), 256, 0, stream>>>(memory, W_mem, nullptr, keys, 32768, 200, 200, 200);
  k_gemm<<<dim3(512, 1), 256, 0, stream>>>(memory, W_attn + 200*50, nullptr, memA, 32768, 50, 200, 50);
  k_gather<<<2048, 256, 0, stream>>>(embeddings, labels, decxA);
  k_gemm<<<dim3(128, 13), 256, 0, stream>>>(decxA, W_dec, b_dec, decx, 8192, 800, 64, 800);
  k_dec_init<<<64, 256, 0, stream>>>(c0h0, nhbuf, ctrs, out);

  hipFuncSetAttribute(reinterpret_cast<const void*>(k_decoder),
                      hipFuncAttributeMaxDynamicSharedMemorySize, DEC_LDS);
  k_decoder<<<256, 256, DEC_LDS, stream>>>(keys, memA, decx, W_dec, W_attn, W_out,
                                           c0h0, sig_len, base_len,
                                           nhbuf, parts, ctrs, out);
}

// Round 2
// 10777.738 us; speedup vs baseline: 1.3236x; 1.3236x over previous
//
#include <hip/hip_runtime.h>

#define B_ 16
#define T_ 2048
#define L_ 512
#define HD 200
#define AT 50

__device__ __forceinline__ float rcp_(float x){ return __builtin_amdgcn_rcpf(x); }
__device__ __forceinline__ float sigf(float x){ return rcp_(1.f + __expf(-x)); }
__device__ __forceinline__ float tanhf_(float x){
  x = fminf(15.f, fmaxf(-15.f, x));
  float e = __expf(-2.f*x);
  return (1.f - e) * rcp_(1.f + e);
}
__device__ __forceinline__ unsigned bf16u(float v){
  unsigned u = __float_as_uint(v);
  u += 0x7FFFu + ((u >> 16) & 1u);
  return u >> 16;
}

// ---------------- conv fold: E[3][256] ----------------
__global__ void k_prep(const float* __restrict__ conv1, const float* __restrict__ conv1a,
                       const float* __restrict__ conv2, const float* __restrict__ conv3,
                       float* __restrict__ E)
{
  __shared__ float K2s[3*256];
  int tid = threadIdx.x;            // 768 threads
  int k = tid >> 8, co = tid & 255;
  float a = 0.f;
  for (int ci = 0; ci < 256; ++ci)
    a = fmaf(conv1[ci], conv2[(k*256 + ci)*256 + co], a);
  K2s[k*256 + co] = a;
  __syncthreads();
  float b2 = 0.f;
  for (int ci = 0; ci < 256; ++ci)
    b2 = fmaf(K2s[k*256 + ci], conv3[ci*256 + co], b2);
  if (k == 1) b2 += conv1a[co];
  E[k*256 + co] = b2;
}

// ---------------- feat[b,t,256] ----------------
__global__ void k_feat(const float* __restrict__ sig, const float* __restrict__ E,
                       const float* __restrict__ c1ab, float* __restrict__ feat)
{
  int idx = blockIdx.x*256 + threadIdx.x;   // grid 8192 -> 32768*64 float4
  int row = idx >> 6;
  int c4  = (idx & 63) * 4;
  int t = row & (T_-1);
  float sm = (t > 0)     ? sig[row-1] : 0.f;
  float s0 = sig[row];
  float sp = (t < T_-1)  ? sig[row+1] : 0.f;
  float4 e0 = *(const float4*)&E[0*256 + c4];
  float4 e1 = *(const float4*)&E[1*256 + c4];
  float4 e2 = *(const float4*)&E[2*256 + c4];
  float4 bb = *(const float4*)&c1ab[c4];
  float4 r;
  r.x = fmaxf(0.f, fmaf(sm, e0.x, fmaf(s0, e1.x, fmaf(sp, e2.x, bb.x))));
  r.y = fmaxf(0.f, fmaf(sm, e0.y, fmaf(s0, e1.y, fmaf(sp, e2.y, bb.y))));
  r.z = fmaxf(0.f, fmaf(sm, e0.z, fmaf(s0, e1.z, fmaf(sp, e2.z, bb.z))));
  r.w = fmaxf(0.f, fmaf(sm, e0.w, fmaf(s0, e1.w, fmaf(sp, e2.w, bb.w))));
  *(float4*)&feat[(size_t)row*256 + c4] = r;
}

// ---------------- generic fp32 GEMM: C[M,N] = A[M,K]*B[K,N] (+bias) ----------------
__global__ __launch_bounds__(256)
void k_gemm(const float* __restrict__ A, const float* __restrict__ B,
            const float* __restrict__ bias, float* __restrict__ C,
            int M, int N, int K, int ldb)
{
  __shared__ float As[16][65];
  __shared__ float Bs[16][65];
  int row0 = blockIdx.x*64, col0 = blockIdx.y*64;
  int tid = threadIdx.x;
  int tm = tid >> 4, tn = tid & 15;
  float acc[4][4] = {};
  for (int k0 = 0; k0 < K; k0 += 16){
    #pragma unroll
    for (int i = 0; i < 4; ++i){
      int e = tid + i*256;
      int m = e >> 4, kk = e & 15;
      float v = 0.f;
      if (k0 + kk < K) v = A[(size_t)(row0+m)*K + k0 + kk];
      As[kk][m] = v;
      int n = e & 63, kb = e >> 6;
      float w = 0.f;
      if (k0 + kb < K && col0 + n < N) w = B[(size_t)(k0+kb)*ldb + col0 + n];
      Bs[kb][n] = w;
    }
    __syncthreads();
    #pragma unroll
    for (int kk = 0; kk < 16; ++kk){
      float a[4], bv[4];
      #pragma unroll
      for (int i = 0; i < 4; ++i){ a[i] = As[kk][tm*4+i]; bv[i] = Bs[kk][tn*4+i]; }
      #pragma unroll
      for (int i = 0; i < 4; ++i)
        #pragma unroll
        for (int j = 0; j < 4; ++j)
          acc[i][j] = fmaf(a[i], bv[j], acc[i][j]);
    }
    __syncthreads();
  }
  #pragma unroll
  for (int i = 0; i < 4; ++i){
    int r = row0 + tm*4 + i;
    #pragma unroll
    for (int j = 0; j < 4; ++j){
      int cc = col0 + tn*4 + j;
      if (cc < N) C[(size_t)r*N + cc] = acc[i][j] + (bias ? bias[cc] : 0.f);
    }
  }
}

// ---------------- weight permute for quad-gate encoder layout ----------------
// Wp[j, u*4+g] = W[j, g*100+u]; row 356 = permuted bias
__global__ void k_permW(const float* __restrict__ Wf, const float* __restrict__ bf,
                        const float* __restrict__ Wb, const float* __restrict__ bb,
                        float* __restrict__ WpF, float* __restrict__ WpB)
{
  int idx = blockIdx.x*256 + threadIdx.x;
  if (idx >= 2*357*400) return;
  int w = idx / (357*400), r = idx - w*(357*400);
  int j = r / 400, col = r - j*400;
  int src = (col & 3)*100 + (col >> 2);
  const float* W = w ? Wb : Wf; const float* bs = w ? bb : bf;
  float v = (j < 356) ? W[j*400 + src] : bs[src];
  (w ? WpB : WpF)[j*400 + col] = v;
}

// ---------------- encoder: quad-gate, 1 barrier/step ----------------
__global__ __launch_bounds__(512, 1)
void k_encoder(const float* __restrict__ xprojF, const float* __restrict__ xprojB,
               const float* __restrict__ WpF, const float* __restrict__ WpB,
               const int* __restrict__ sig_len, float* __restrict__ memory,
               float* __restrict__ c0h0, int dirParam)
{
  int dir, b;
  if (dirParam < 0){ dir = blockIdx.x & 1; b = blockIdx.x >> 1; }
  else             { dir = dirParam;       b = blockIdx.x; }
  const float* xp = dir ? xprojB : xprojF;
  const float* Wp = dir ? WpB : WpF;
  int tid = threadIdx.x;
  int u = tid >> 2, gq = tid & 3;
  __shared__ __align__(16) float h2[2][104];
  float U[100];
  if (tid < 400){
    #pragma unroll
    for (int j = 0; j < 100; ++j) U[j] = Wp[(256 + j)*400 + tid];
  }
  if (tid < 100) h2[0][tid] = 0.f;
  int len = sig_len[b];
  float c = 0.f, hfin = 0.f;
  float xb0 = 0.f, xb1 = 0.f;
  if (tid < 400){
    int ta = dir ? (len-1) : 0;
    xb0 = xp[((size_t)(b*T_ + ta))*400 + tid];
    if (len > 1){
      int tb_ = dir ? (len-2) : 1;
      xb1 = xp[((size_t)(b*T_ + tb_))*400 + tid];
    }
  }
  for (int step = 0; step < len; ++step){
    __syncthreads();
    float z = xb0;
    float xn = 0.f;
    if (tid < 400){
      if (step + 2 < len){
        int tn = dir ? (len-3-step) : (step+2);
        xn = xp[((size_t)(b*T_ + tn))*400 + tid];
      }
      const float* hb = h2[step & 1];
      float a0 = z, a1 = 0.f, a2 = 0.f, a3 = 0.f;
      #pragma unroll
      for (int j4 = 0; j4 < 25; ++j4){
        float4 h4 = *(const float4*)&hb[j4*4];
        a0 = fmaf(h4.x, U[j4*4+0], a0);
        a1 = fmaf(h4.y, U[j4*4+1], a1);
        a2 = fmaf(h4.z, U[j4*4+2], a2);
        a3 = fmaf(h4.w, U[j4*4+3], a3);
      }
      z = (a0+a1)+(a2+a3);
    }
    // quad all-gather via shuffles: v_m = z[lane ^ m]
    float v0 = z, v1 = __shfl_xor(z, 1);
    float v2 = __shfl_xor(v0, 2), v3 = __shfl_xor(v1, 2);
    if (tid < 400){
      float tA  = (gq&1) ? v1 : v0, tB  = (gq&1) ? v3 : v2;
      float tA2 = (gq&1) ? v0 : v1, tB2 = (gq&1) ? v2 : v3;
      float zi = (gq&2) ? tB  : tA;
      float zj = (gq&2) ? tB2 : tA2;
      float zf = (gq&2) ? tA  : tB;
      float zo = (gq&2) ? tA2 : tB2;
      c = c*sigf(zf + 1.f) + sigf(zi)*tanhf_(zj);
      float nh = tanhf_(c)*sigf(zo);
      hfin = nh;
      if (gq == 0){
        int t = dir ? (len-1-step) : step;
        h2[(step+1)&1][u] = nh;
        memory[((size_t)(b*T_ + t))*200 + dir*100 + u] = nh;
      }
      xb0 = xb1; xb1 = xn;
    }
  }
  if (tid < 400 && gq == 0){
    c0h0[b*400 + dir*100 + u]       = c;
    c0h0[b*400 + 200 + dir*100 + u] = hfin;
  }
  int total = (T_ - len)*100;
  for (int i = tid; i < total; i += 512){
    int t = len + i/100;
    int k = i - (i/100)*100;
    memory[((size_t)(b*T_ + t))*200 + dir*100 + k] = 0.f;
  }
}

// ---------------- decoder input gather ----------------
__global__ void k_gather(const float* __restrict__ emb, const int* __restrict__ labels,
                         float* __restrict__ dA)
{
  int idx = blockIdx.x*256 + threadIdx.x;  // grid 2048
  int i = idx >> 6, e = idx & 63;
  dA[(size_t)i*64 + e] = emb[labels[i]*64 + e];
}

// ---------------- decoder init: zero out, reset ctrs ----------------
__global__ void k_dec_init(unsigned int* __restrict__ ctrs, float* __restrict__ out)
{
  int idx = blockIdx.x*256 + threadIdx.x;   // grid 192 -> 49152
  if (idx < B_*L_*6) out[idx] = 0.f;
  if (idx < 32) ctrs[idx] = 0u;
}

// ---------------- cooperative decoder: 16 blocks per batch item ----------------
#define DEC_LDS 137600
#define TCH 128

__global__ __launch_bounds__(256, 1)
void k_decoder(const float* __restrict__ keysG, const float* __restrict__ memAG,
               const float* __restrict__ decx,  const float* __restrict__ W_dec,
               const float* __restrict__ W_attn, const float* __restrict__ W_out,
               const float* __restrict__ c0h0, const int* __restrict__ sig_len,
               const int* __restrict__ base_len,
               float* nhbuf, float* partials, unsigned int* ctrs,
               float* __restrict__ out)
{
  int blk = blockIdx.x;
  int b = (blk & 7) | (((blk >> 3) & 1) << 3);   // b's 16 blocks -> same XCD (blk%8 const)
  int g = blk >> 4;
  int tid = threadIdx.x;
  int u0 = g * 13;
  int nu = (HD - u0 < 13) ? (HD - u0) : 13;      // 13 (g<15) or 5 (g==15)
  int t0 = g * TCH;

  extern __shared__ char smem[];
  uint2* keyP  = (uint2*)(smem);                 // [p<50][t<128+pad] stride 129: key[t][4p..4p+3] bf16
  float* memAL = (float*)(smem + 51616);         // [128][50]
  float* Uld   = (float*)(smem + 77216);         // [250][52]  rows: 0..49 attn, 50..249 h
  float* Wa1s  = (float*)(smem + 129216);        // [13][50]
  float* WoutL = (float*)(smem + 131824);        // [50][6]
  float* nhF   = (float*)(smem + 133024);        // [208] (tail zeroed)
  float* spL   = (float*)(smem + 133856);        // [256]
  float* wL    = (float*)(smem + 134880);        // [128]
  float* cpL   = (float*)(smem + 135392);        // [3][52]
  float* apL   = (float*)(smem + 136016);        // [50]
  float* zp    = (float*)(smem + 136224);        // [52][4]
  float* zfu   = (float*)(smem + 137056);        // [52]
  float* cL    = (float*)(smem + 137264);        // [13]
  float* attnL = (float*)(smem + 137328);        // [50]
  float* SL    = (float*)(smem + 137528);        // [1]

  // ---- one-time fills (coalesced) ----
  for (int i = tid; i < TCH*50; i += 256){
    int t = i / 50, p = i - (i/50)*50;
    float4 kv = *(const float4*)&keysG[((size_t)(b*T_ + t0 + t))*200 + 4*p];
    keyP[p*129 + t] = make_uint2(bf16u(kv.x) | (bf16u(kv.y) << 16),
                                 bf16u(kv.z) | (bf16u(kv.w) << 16));
    memAL[t*50 + p] = memAG[((size_t)(b*T_ + t0 + t))*50 + p];
  }
  for (int i = tid; i < 250*52; i += 256){
    int j = i / 52, o_ = i - (i/52)*52;
    int uu = o_ >> 2, gg = o_ & 3;
    Uld[i] = (uu < nu) ? W_dec[(size_t)(64 + j)*800 + gg*200 + u0 + uu] : 0.f;
  }
  for (int i = tid; i < 13*50; i += 256){
    int uu = i / 50, d = i - (i/50)*50;
    Wa1s[i] = (uu < nu) ? W_attn[(size_t)(u0 + uu)*50 + d] : 0.f;
  }
  for (int i = tid; i < 300; i += 256) WoutL[i] = W_out[i];
  if (tid < nu) cL[tid] = c0h0[b*400 + u0 + tid];
  if (tid < 50) attnL[tid] = 0.f;
  if (tid < 8)  nhF[200 + tid] = 0.f;
  int len = sig_len[b];
  int Lb  = base_len[b];
  unsigned int* ctrA = ctrs + b*2;
  unsigned int* ctrB = ctrA + 1;
  __syncthreads();

  // ---- pre-loop: nhF = h0; zh(0); dcx(0) ----
  if (tid < 50) *(float4*)&nhF[tid*4] = *(const float4*)&c0h0[b*400 + 200 + tid*4];
  __syncthreads();
  int o  = tid - (tid/52)*52;
  int jc = tid / 52;
  float zh = 0.f, dcx = 0.f;
  if (tid < 208){
    const float* Ub = &Uld[(50 + jc*50)*52 + o];
    const float* hp = &nhF[jc*50];
    #pragma unroll 10
    for (int j = 0; j < 50; ++j) zh = fmaf(hp[j], Ub[(size_t)j*52], zh);
    if (jc == 0) dcx = decx[((size_t)(b*L_))*800 + (o&3)*200 + u0 + (o>>2)];
  }

  for (int l = 0; l < Lb; ++l){
    // ---- P1: za (attn rows) + combine; g1 writes out(l-1)
    if (tid < 208){
      float z = zh + ((jc == 0) ? dcx : 0.f);
      const float* Ub = &Uld[(jc*13)*52 + o];
      const float* ap_ = &attnL[jc*13];
      int cnt = (jc < 3) ? 13 : 11;
      for (int j = 0; j < cnt; ++j) z = fmaf(ap_[j], Ub[(size_t)j*52], z);
      zp[o*4 + jc] = z;
    } else if (g == 1 && l > 0 && tid < 214){
      int j = tid - 208;
      float o_ = 0.f;
      for (int d = 0; d < AT; ++d) o_ = fmaf(attnL[d], WoutL[d*6 + j], o_);
      out[((size_t)(b*L_ + (l-1)))*6 + j] = o_;
    }
    __syncthreads();
    if (tid < 52) zfu[tid] = (zp[tid*4] + zp[tid*4+1]) + (zp[tid*4+2] + zp[tid*4+3]);
    __syncthreads();
    if (tid < nu){
      float4 zz = *(const float4*)&zfu[tid*4];
      float c = cL[tid];
      c = c*sigf(zz.z + 1.f) + sigf(zz.x)*tanhf_(zz.y);
      cL[tid] = c;
      float nh = tanhf_(c)*sigf(zz.w);
      nhbuf[((size_t)(l&1)*B_ + b)*HD + u0 + tid] = nh;
    }
    __syncthreads();
    // ---- barrier A (nh slices published)
    if (tid == 0){
      __hip_atomic_fetch_add(ctrA, 1u, __ATOMIC_RELEASE, __HIP_MEMORY_SCOPE_AGENT);
      unsigned tgt = 16u*(unsigned)(l+1);
      while (__hip_atomic_load(ctrA, __ATOMIC_RELAXED, __HIP_MEMORY_SCOPE_AGENT) < tgt)
        __builtin_amdgcn_s_sleep(1);
      __builtin_amdgcn_fence(__ATOMIC_ACQUIRE, "agent");
    }
    __syncthreads();
    if (tid < 50)
      *(float4*)&nhF[tid*4] = *(const float4*)&nhbuf[((size_t)(l&1)*B_ + b)*HD + tid*4];
    __syncthreads();
    // ---- scores over t-chunk (bf16 keys, conflict-free)
    {
      int t = tid & 127, dh = tid >> 7;
      const uint2* kp = &keyP[(dh*25)*129 + t];
      const float4* nf = (const float4*)nhF + dh*25;
      float s0 = 0.f, s1 = 0.f;
      #pragma unroll
      for (int q = 0; q < 25; ++q){
        uint2 kk = kp[(size_t)q*129];
        float4 nv = nf[q];
        s0 = fmaf(nv.x, __uint_as_float(kk.x << 16), s0);
        s1 = fmaf(nv.y, __uint_as_float(kk.x & 0xFFFF0000u), s1);
        s0 = fmaf(nv.z, __uint_as_float(kk.y << 16), s0);
        s1 = fmaf(nv.w, __uint_as_float(kk.y & 0xFFFF0000u), s1);
      }
      spL[tid] = s0 + s1;
    }
    __syncthreads();
    if (tid < 128){
      float s = spL[tid] + spL[tid + 128];
      float w = 0.f;
      if (t0 + tid < len){ s = fminf(60.f, fmaxf(-60.f, s)); w = __expf(s); }
      wL[tid] = w;
    } else if (tid < 178){
      int d = tid - 128;
      float a = 0.f;
      #pragma unroll
      for (int uu = 0; uu < 13; ++uu) a = fmaf(nhF[u0 + uu], Wa1s[uu*50 + d], a);
      apL[d] = a;
    }
    __syncthreads();
    if (tid >= 192){
      float v = wL[tid - 192] + wL[tid - 128];
      #pragma unroll
      for (int off = 32; off > 0; off >>= 1) v += __shfl_down(v, off);
      if (tid == 192) SL[0] = v;
    } else {
      int tc = tid >> 6, d = tid & 63;
      if (d < 50){
        int tlo = tc*43, thi = (tc == 2) ? 128 : tc*43 + 43;
        float a = 0.f;
        for (int t = tlo; t < thi; ++t) a = fmaf(wL[t], memAL[t*50 + d], a);
        cpL[tc*52 + d] = a;
      }
    }
    __syncthreads();
    {
      float* pb = partials + ((size_t)(b*16 + g))*128;
      if (tid < 50){
        pb[tid]      = (cpL[tid] + cpL[52 + tid]) + cpL[104 + tid];
        pb[64 + tid] = apL[tid];
      } else if (tid == 50) pb[127] = SL[0];
    }
    __syncthreads();
    // ---- barrier B arrive; zh(l+1)+dcx(l+1) hidden under the wait
    if (tid == 0)
      __hip_atomic_fetch_add(ctrB, 1u, __ATOMIC_RELEASE, __HIP_MEMORY_SCOPE_AGENT);
    zh = 0.f;
    if (tid < 208){
      const float* Ub = &Uld[(50 + jc*50)*52 + o];
      const float* hp = &nhF[jc*50];
      #pragma unroll 10
      for (int j = 0; j < 50; ++j) zh = fmaf(hp[j], Ub[(size_t)j*52], zh);
      if (jc == 0 && l+1 < Lb)
        dcx = decx[((size_t)(b*L_ + (l+1)))*800 + (o&3)*200 + u0 + (o>>2)];
    }
    if (tid == 0){
      unsigned tgt = 16u*(unsigned)(l+1);
      while (__hip_atomic_load(ctrB, __ATOMIC_RELAXED, __HIP_MEMORY_SCOPE_AGENT) < tgt)
        __builtin_amdgcn_s_sleep(1);
      __builtin_amdgcn_fence(__ATOMIC_ACQUIRE, "agent");
    }
    __syncthreads();
    // ---- reduce partials -> attn (replicated in every block)
    if (tid < 50){
      float cs = 0.f, as = 0.f, Ss = 0.f;
      #pragma unroll
      for (int gg = 0; gg < 16; ++gg){
        const float* pq = partials + ((size_t)(b*16 + gg))*128;
        cs += pq[tid]; as += pq[64 + tid]; Ss += pq[127];
      }
      attnL[tid] = fmaf(cs, rcp_(Ss), as);
    }
    __syncthreads();
  }
  // tail: out(Lb-1)
  if (g == 1 && tid < 6){
    float o_ = 0.f;
    for (int d = 0; d < AT; ++d) o_ = fmaf(attnL[d], WoutL[d*6 + tid], o_);
    out[((size_t)(b*L_ + (Lb-1)))*6 + tid] = o_;
  }
}

extern "C" void kernel_launch(void* const* d_in, const int* in_sizes, int n_in,
                              void* d_out, int out_size, void* d_ws, size_t ws_size,
                              hipStream_t stream)
{
  const float* signals   = (const float*)d_in[0];
  const float* embeddings= (const float*)d_in[1];
  const float* conv1_k   = (const float*)d_in[2];
  const float* conv1a_k  = (const float*)d_in[3];
  const float* conv1a_b  = (const float*)d_in[4];
  const float* conv2_k   = (const float*)d_in[5];
  const float* conv3_k   = (const float*)d_in[6];
  const float* W_fwd     = (const float*)d_in[7];
  const float* b_fwd     = (const float*)d_in[8];
  const float* W_bwd     = (const float*)d_in[9];
  const float* b_bwd     = (const float*)d_in[10];
  const float* W_dec     = (const float*)d_in[11];
  const float* b_dec     = (const float*)d_in[12];
  const float* W_mem     = (const float*)d_in[13];
  const float* W_attn    = (const float*)d_in[14];
  const float* W_out     = (const float*)d_in[15];
  const int*   labels    = (const int*)d_in[16];
  const int*   sig_len   = (const int*)d_in[17];
  const int*   base_len  = (const int*)d_in[18];
  float* out = (float*)d_out;
  char* ws = (char*)d_ws;

  const size_t o_E        = 0;
  const size_t o_c0h0     = 4096;
  const size_t o_nhbuf    = 32768;        // 2*16*200*4 = 25600
  const size_t o_partials = 65536;        // 16*16*128*4 = 131072
  const size_t o_ctr      = 524288;       // 32 u32
  const size_t o_WpF      = 589824;       // 357*400*4 = 571200
  const size_t o_WpB      = 1161024;
  const size_t o_feat     = 4194304;      // feat 33.5MB; keys overlays
  const size_t o_mem      = o_feat + 33554432;   // memory 26.2MB
  const size_t o_X1       = o_mem + 26214400;    // 52.4MB xprojF / memA+decx overlay
  const size_t o_X2       = o_X1 + 52428800;     // xprojB when ws big enough

  bool bigws = (ws_size >= o_X2 + 52428800);

  float* E      = (float*)(ws + o_E);
  float* c0h0   = (float*)(ws + o_c0h0);
  float* nhbuf  = (float*)(ws + o_nhbuf);
  float* parts  = (float*)(ws + o_partials);
  unsigned int* ctrs = (unsigned int*)(ws + o_ctr);
  float* WpF    = (float*)(ws + o_WpF);
  float* WpB    = (float*)(ws + o_WpB);
  float* feat   = (float*)(ws + o_feat);
  float* keys   = feat;                          // overlay after encoder
  float* memory = (float*)(ws + o_mem);
  float* xprojF = (float*)(ws + o_X1);
  float* xprojB = bigws ? (float*)(ws + o_X2) : xprojF;
  float* memA   = (float*)(ws + o_X1);           // overlay after encoder
  float* decxA  = (float*)(ws + o_X1 + 6553600);
  float* decx   = (float*)(ws + o_X1 + 8650752);

  k_prep<<<1, 768, 0, stream>>>(conv1_k, conv1a_k, conv2_k, conv3_k, E);
  k_feat<<<8192, 256, 0, stream>>>(signals, E, conv1a_b, feat);
  k_permW<<<1116, 256, 0, stream>>>(W_fwd, b_fwd, W_bwd, b_bwd, WpF, WpB);

  dim3 gx(512, 7);
  if (bigws){
    k_gemm<<<gx, 256, 0, stream>>>(feat, WpF, WpF + 356*400, xprojF, 32768, 400, 256, 400);
    k_gemm<<<gx, 256, 0, stream>>>(feat, WpB, WpB + 356*400, xprojB, 32768, 400, 256, 400);
    k_encoder<<<32, 512, 0, stream>>>(xprojF, xprojB, WpF, WpB, sig_len, memory, c0h0, -1);
  } else {
    k_gemm<<<gx, 256, 0, stream>>>(feat, WpF, WpF + 356*400, xprojF, 32768, 400, 256, 400);
    k_encoder<<<16, 512, 0, stream>>>(xprojF, xprojF, WpF, WpB, sig_len, memory, c0h0, 0);
    k_gemm<<<gx, 256, 0, stream>>>(feat, WpB, WpB + 356*400, xprojF, 32768, 400, 256, 400);
    k_encoder<<<16, 512, 0, stream>>>(xprojF, xprojF, WpF, WpB, sig_len, memory, c0h0, 1);
  }

  k_gemm<<<dim3(512, 4), 256, 0, stream>>>(memory, W_mem, nullptr, keys, 32768, 200, 200, 200);
  k_gemm<<<dim3(512, 1), 256, 0, stream>>>(memory, W_attn + 200*50, nullptr, memA, 32768, 50, 200, 50);
  k_gather<<<2048, 256, 0, stream>>>(embeddings, labels, decxA);
  k_gemm<<<dim3(128, 13), 256, 0, stream>>>(decxA, W_dec, b_dec, decx, 8192, 800, 64, 800);
  k_dec_init<<<192, 256, 0, stream>>>(ctrs, out);

  hipFuncSetAttribute(reinterpret_cast<const void*>(k_decoder),
                      hipFuncAttributeMaxDynamicSharedMemorySize, DEC_LDS);
  k_decoder<<<256, 256, DEC_LDS, stream>>>(keys, memA, decx, W_dec, W_attn, W_out,
                                           c0h0, sig_len, base_len,
                                           nhbuf, parts, ctrs, out);
}

// Round 3
// 6889.623 us; speedup vs baseline: 2.0705x; 1.5643x over previous
//
#include <hip/hip_runtime.h>

#define B_ 16
#define T_ 2048
#define L_ 512
#define HD 200
#define AT 50

__device__ __forceinline__ float rcp_(float x){ return __builtin_amdgcn_rcpf(x); }
__device__ __forceinline__ float sigf(float x){ return rcp_(1.f + __expf(-x)); }
__device__ __forceinline__ float tanhf_(float x){
  x = fminf(15.f, fmaxf(-15.f, x));
  float e = __expf(-2.f*x);
  return (1.f - e) * rcp_(1.f + e);
}
__device__ __forceinline__ unsigned bf16u(float v){
  unsigned u = __float_as_uint(v);
  u += 0x7FFFu + ((u >> 16) & 1u);
  return u >> 16;
}
__device__ __forceinline__ unsigned long long pk2(float a, float b){
  return (unsigned long long)__float_as_uint(a) |
         ((unsigned long long)__float_as_uint(b) << 32);
}

// ---------------- conv fold: E[3][256] ----------------
__global__ void k_prep(const float* __restrict__ conv1, const float* __restrict__ conv1a,
                       const float* __restrict__ conv2, const float* __restrict__ conv3,
                       float* __restrict__ E)
{
  __shared__ float K2s[3*256];
  int tid = threadIdx.x;            // 768 threads
  int k = tid >> 8, co = tid & 255;
  float a = 0.f;
  for (int ci = 0; ci < 256; ++ci)
    a = fmaf(conv1[ci], conv2[(k*256 + ci)*256 + co], a);
  K2s[k*256 + co] = a;
  __syncthreads();
  float b2 = 0.f;
  for (int ci = 0; ci < 256; ++ci)
    b2 = fmaf(K2s[k*256 + ci], conv3[ci*256 + co], b2);
  if (k == 1) b2 += conv1a[co];
  E[k*256 + co] = b2;
}

// ---------------- feat[b,t,256] ----------------
__global__ void k_feat(const float* __restrict__ sig, const float* __restrict__ E,
                       const float* __restrict__ c1ab, float* __restrict__ feat)
{
  int idx = blockIdx.x*256 + threadIdx.x;   // grid 8192 -> 32768*64 float4
  int row = idx >> 6;
  int c4  = (idx & 63) * 4;
  int t = row & (T_-1);
  float sm = (t > 0)     ? sig[row-1] : 0.f;
  float s0 = sig[row];
  float sp = (t < T_-1)  ? sig[row+1] : 0.f;
  float4 e0 = *(const float4*)&E[0*256 + c4];
  float4 e1 = *(const float4*)&E[1*256 + c4];
  float4 e2 = *(const float4*)&E[2*256 + c4];
  float4 bb = *(const float4*)&c1ab[c4];
  float4 r;
  r.x = fmaxf(0.f, fmaf(sm, e0.x, fmaf(s0, e1.x, fmaf(sp, e2.x, bb.x))));
  r.y = fmaxf(0.f, fmaf(sm, e0.y, fmaf(s0, e1.y, fmaf(sp, e2.y, bb.y))));
  r.z = fmaxf(0.f, fmaf(sm, e0.z, fmaf(s0, e1.z, fmaf(sp, e2.z, bb.z))));
  r.w = fmaxf(0.f, fmaf(sm, e0.w, fmaf(s0, e1.w, fmaf(sp, e2.w, bb.w))));
  *(float4*)&feat[(size_t)row*256 + c4] = r;
}

// ---------------- generic fp32 GEMM: C[M,N] = A[M,K]*B[K,N] (+bias) ----------------
__global__ __launch_bounds__(256)
void k_gemm(const float* __restrict__ A, const float* __restrict__ B,
            const float* __restrict__ bias, float* __restrict__ C,
            int M, int N, int K, int ldb)
{
  __shared__ float As[16][65];
  __shared__ float Bs[16][65];
  int row0 = blockIdx.x*64, col0 = blockIdx.y*64;
  int tid = threadIdx.x;
  int tm = tid >> 4, tn = tid & 15;
  float acc[4][4] = {};
  for (int k0 = 0; k0 < K; k0 += 16){
    #pragma unroll
    for (int i = 0; i < 4; ++i){
      int e = tid + i*256;
      int m = e >> 4, kk = e & 15;
      float v = 0.f;
      if (k0 + kk < K) v = A[(size_t)(row0+m)*K + k0 + kk];
      As[kk][m] = v;
      int n = e & 63, kb = e >> 6;
      float w = 0.f;
      if (k0 + kb < K && col0 + n < N) w = B[(size_t)(k0+kb)*ldb + col0 + n];
      Bs[kb][n] = w;
    }
    __syncthreads();
    #pragma unroll
    for (int kk = 0; kk < 16; ++kk){
      float a[4], bv[4];
      #pragma unroll
      for (int i = 0; i < 4; ++i){ a[i] = As[kk][tm*4+i]; bv[i] = Bs[kk][tn*4+i]; }
      #pragma unroll
      for (int i = 0; i < 4; ++i)
        #pragma unroll
        for (int j = 0; j < 4; ++j)
          acc[i][j] = fmaf(a[i], bv[j], acc[i][j]);
    }
    __syncthreads();
  }
  #pragma unroll
  for (int i = 0; i < 4; ++i){
    int r = row0 + tm*4 + i;
    #pragma unroll
    for (int j = 0; j < 4; ++j){
      int cc = col0 + tn*4 + j;
      if (cc < N) C[(size_t)r*N + cc] = acc[i][j] + (bias ? bias[cc] : 0.f);
    }
  }
}

// ---------------- weight permute for quad-gate encoder layout ----------------
__global__ void k_permW(const float* __restrict__ Wf, const float* __restrict__ bf,
                        const float* __restrict__ Wb, const float* __restrict__ bb,
                        float* __restrict__ WpF, float* __restrict__ WpB)
{
  int idx = blockIdx.x*256 + threadIdx.x;
  if (idx >= 2*357*400) return;
  int w = idx / (357*400), r = idx - w*(357*400);
  int j = r / 400, col = r - j*400;
  int src = (col & 3)*100 + (col >> 2);
  const float* W = w ? Wb : Wf; const float* bs = w ? bb : bf;
  float v = (j < 356) ? W[j*400 + src] : bs[src];
  (w ? WpB : WpF)[j*400 + col] = v;
}

// ---------------- encoder: quad-gate, 1 barrier/step ----------------
__global__ __launch_bounds__(512, 1)
void k_encoder(const float* __restrict__ xprojF, const float* __restrict__ xprojB,
               const float* __restrict__ WpF, const float* __restrict__ WpB,
               const int* __restrict__ sig_len, float* __restrict__ memory,
               float* __restrict__ c0h0, int dirParam)
{
  int dir, b;
  if (dirParam < 0){ dir = blockIdx.x & 1; b = blockIdx.x >> 1; }
  else             { dir = dirParam;       b = blockIdx.x; }
  const float* xp = dir ? xprojB : xprojF;
  const float* Wp = dir ? WpB : WpF;
  int tid = threadIdx.x;
  int u = tid >> 2, gq = tid & 3;
  __shared__ __align__(16) float h2[2][104];
  float U[100];
  if (tid < 400){
    #pragma unroll
    for (int j = 0; j < 100; ++j) U[j] = Wp[(256 + j)*400 + tid];
  }
  if (tid < 100) h2[0][tid] = 0.f;
  int len = sig_len[b];
  float c = 0.f, hfin = 0.f;
  float xb0 = 0.f, xb1 = 0.f;
  if (tid < 400){
    int ta = dir ? (len-1) : 0;
    xb0 = xp[((size_t)(b*T_ + ta))*400 + tid];
    if (len > 1){
      int tb_ = dir ? (len-2) : 1;
      xb1 = xp[((size_t)(b*T_ + tb_))*400 + tid];
    }
  }
  for (int step = 0; step < len; ++step){
    __syncthreads();
    float z = xb0;
    float xn = 0.f;
    if (tid < 400){
      if (step + 2 < len){
        int tn = dir ? (len-3-step) : (step+2);
        xn = xp[((size_t)(b*T_ + tn))*400 + tid];
      }
      const float* hb = h2[step & 1];
      float a0 = z, a1 = 0.f, a2 = 0.f, a3 = 0.f;
      #pragma unroll
      for (int j4 = 0; j4 < 25; ++j4){
        float4 h4 = *(const float4*)&hb[j4*4];
        a0 = fmaf(h4.x, U[j4*4+0], a0);
        a1 = fmaf(h4.y, U[j4*4+1], a1);
        a2 = fmaf(h4.z, U[j4*4+2], a2);
        a3 = fmaf(h4.w, U[j4*4+3], a3);
      }
      z = (a0+a1)+(a2+a3);
    }
    float v0 = z, v1 = __shfl_xor(z, 1);
    float v2 = __shfl_xor(v0, 2), v3 = __shfl_xor(v1, 2);
    if (tid < 400){
      float tA  = (gq&1) ? v1 : v0, tB  = (gq&1) ? v3 : v2;
      float tA2 = (gq&1) ? v0 : v1, tB2 = (gq&1) ? v2 : v3;
      float zi = (gq&2) ? tB  : tA;
      float zj = (gq&2) ? tB2 : tA2;
      float zf = (gq&2) ? tA  : tB;
      float zo = (gq&2) ? tA2 : tB2;
      c = c*sigf(zf + 1.f) + sigf(zi)*tanhf_(zj);
      float nh = tanhf_(c)*sigf(zo);
      hfin = nh;
      if (gq == 0){
        int t = dir ? (len-1-step) : step;
        h2[(step+1)&1][u] = nh;
        memory[((size_t)(b*T_ + t))*200 + dir*100 + u] = nh;
      }
      xb0 = xb1; xb1 = xn;
    }
  }
  if (tid < 400 && gq == 0){
    c0h0[b*400 + dir*100 + u]       = c;
    c0h0[b*400 + 200 + dir*100 + u] = hfin;
  }
  int total = (T_ - len)*100;
  for (int i = tid; i < total; i += 512){
    int t = len + i/100;
    int k = i - (i/100)*100;
    memory[((size_t)(b*T_ + t))*200 + dir*100 + k] = 0.f;
  }
}

// ---------------- decoder input gather ----------------
__global__ void k_gather(const float* __restrict__ emb, const int* __restrict__ labels,
                         float* __restrict__ dA)
{
  int idx = blockIdx.x*256 + threadIdx.x;  // grid 2048
  int i = idx >> 6, e = idx & 63;
  dA[(size_t)i*64 + e] = emb[labels[i]*64 + e];
}

// ---------------- decoder init: zero out, reset ctrs ----------------
__global__ void k_dec_init(unsigned int* __restrict__ ctrs, float* __restrict__ out)
{
  int idx = blockIdx.x*256 + threadIdx.x;   // grid 192 -> 49152
  if (idx < B_*L_*6) out[idx] = 0.f;
  if (idx < 32) ctrs[idx] = 0u;
}

// ---------------- cooperative decoder: 16 blocks per batch item ----------------
// All cross-block mutable data (nhbuf, partials, ctrs) is accessed ONLY via
// relaxed agent-scope atomics (sc1, L2-bypass, coherent at IF) -> no
// buffer_inv/buffer_wbl2 cache maintenance. Ordering: __syncthreads drains
// vmcnt; workgroup-scope fence (s_waitcnt only) orders stores vs the flag RMW
// at the common coherence point.
#define DEC_LDS 138240
#define TCH 128

__global__ __launch_bounds__(256, 1)
void k_decoder(const float* __restrict__ keysG, const float* __restrict__ memAG,
               const float* __restrict__ decx,  const float* __restrict__ W_dec,
               const float* __restrict__ W_attn, const float* __restrict__ W_out,
               const float* __restrict__ c0h0, const int* __restrict__ sig_len,
               const int* __restrict__ base_len,
               float* nhbuf, float* partials, unsigned int* ctrs,
               float* __restrict__ out)
{
  int blk = blockIdx.x;
  int b = (blk & 7) | (((blk >> 3) & 1) << 3);   // b's 16 blocks -> same XCD (blk%8 const)
  int g = blk >> 4;
  int tid = threadIdx.x;
  int u0 = g * 13;
  int nu = (HD - u0 < 13) ? (HD - u0) : 13;      // 13 (g<15) or 5 (g==15)
  int t0 = g * TCH;

  extern __shared__ char smem[];
  uint2* keyP  = (uint2*)(smem);                 // [p<50][t<128+pad] stride 129
  float* memAL = (float*)(smem + 51616);         // [128][50]
  float* Uld   = (float*)(smem + 77216);         // [250][52]  rows: 0..49 attn, 50..249 h
  float* Wa1s  = (float*)(smem + 129216);        // [13][50]
  float* WoutL = (float*)(smem + 131824);        // [50][6]
  float* nhF   = (float*)(smem + 133024);        // [208] (tail zeroed)
  float* spL   = (float*)(smem + 133856);        // [256]
  float* wL    = (float*)(smem + 134880);        // [128]
  float* cpL   = (float*)(smem + 135392);        // [3][52]
  float* apL   = (float*)(smem + 136016);        // [52]
  float* zp    = (float*)(smem + 136224);        // [52][4]
  float* cL    = (float*)(smem + 137120);        // [13]
  float* attnL = (float*)(smem + 137184);        // [50]
  float* SL    = (float*)(smem + 137384);        // [1]
  float* ctxR  = (float*)(smem + 137392);        // [52]
  float* apR   = (float*)(smem + 137600);        // [52]

  // ---- one-time fills (coalesced) ----
  for (int i = tid; i < TCH*50; i += 256){
    int t = i / 50, p = i - (i/50)*50;
    float4 kv = *(const float4*)&keysG[((size_t)(b*T_ + t0 + t))*200 + 4*p];
    keyP[p*129 + t] = make_uint2(bf16u(kv.x) | (bf16u(kv.y) << 16),
                                 bf16u(kv.z) | (bf16u(kv.w) << 16));
    memAL[t*50 + p] = memAG[((size_t)(b*T_ + t0 + t))*50 + p];
  }
  for (int i = tid; i < 250*52; i += 256){
    int j = i / 52, o_ = i - (i/52)*52;
    int uu = o_ >> 2, gg = o_ & 3;
    Uld[i] = (uu < nu) ? W_dec[(size_t)(64 + j)*800 + gg*200 + u0 + uu] : 0.f;
  }
  for (int i = tid; i < 13*50; i += 256){
    int uu = i / 50, d = i - (i/50)*50;
    Wa1s[i] = (uu < nu) ? W_attn[(size_t)(u0 + uu)*50 + d] : 0.f;
  }
  for (int i = tid; i < 300; i += 256) WoutL[i] = W_out[i];
  if (tid < nu) cL[tid] = c0h0[b*400 + u0 + tid];
  if (tid < 50) attnL[tid] = 0.f;
  if (tid < 8)  nhF[200 + tid] = 0.f;
  int len = sig_len[b];
  int Lb  = base_len[b];
  unsigned int* ctrA = ctrs + b*2;
  unsigned int* ctrB = ctrA + 1;
  __syncthreads();

  // ---- pre-loop: nhF = h0; zh(0); dcx(0) ----
  if (tid < 50) *(float4*)&nhF[tid*4] = *(const float4*)&c0h0[b*400 + 200 + tid*4];
  __syncthreads();
  int o  = tid - (tid/52)*52;
  int jc = tid / 52;
  float zh = 0.f, dcx = 0.f;
  if (tid < 208){
    const float* Ub = &Uld[(50 + jc*50)*52 + o];
    const float* hp = &nhF[jc*50];
    #pragma unroll 10
    for (int j = 0; j < 50; ++j) zh = fmaf(hp[j], Ub[(size_t)j*52], zh);
    if (jc == 0) dcx = decx[((size_t)(b*L_))*800 + (o&3)*200 + u0 + (o>>2)];
  }

  for (int l = 0; l < Lb; ++l){
    // ---- P1: za (attn rows) + combine; g1 writes out(l-1)
    if (tid < 208){
      float z = zh + ((jc == 0) ? dcx : 0.f);
      const float* Ub = &Uld[(jc*13)*52 + o];
      const float* ap_ = &attnL[jc*13];
      int cnt = (jc < 3) ? 13 : 11;
      for (int j = 0; j < cnt; ++j) z = fmaf(ap_[j], Ub[(size_t)j*52], z);
      zp[o*4 + jc] = z;
    } else if (g == 1 && l > 0 && tid < 214){
      int j = tid - 208;
      float o_ = 0.f;
      for (int d = 0; d < AT; ++d) o_ = fmaf(attnL[d], WoutL[d*6 + j], o_);
      out[((size_t)(b*L_ + (l-1)))*6 + j] = o_;
    }
    __syncthreads();
    // ---- fused combine + activation + publish nh slice
    if (tid < nu){
      const float* zz = &zp[(4*tid)*4];
      float zi = (zz[0]+zz[1])+(zz[2]+zz[3]);
      float zj = (zz[4]+zz[5])+(zz[6]+zz[7]);
      float zf = (zz[8]+zz[9])+(zz[10]+zz[11]);
      float zo = (zz[12]+zz[13])+(zz[14]+zz[15]);
      float c = cL[tid];
      c = c*sigf(zf + 1.f) + sigf(zi)*tanhf_(zj);
      cL[tid] = c;
      float nh = tanhf_(c)*sigf(zo);
      __hip_atomic_store(&nhbuf[((size_t)(l&1)*B_ + b)*HD + u0 + tid], nh,
                         __ATOMIC_RELAXED, __HIP_MEMORY_SCOPE_AGENT);
    }
    __syncthreads();                       // drains vmcnt -> stores at IF
    // ---- barrier A (nh slices published); fence-light
    if (tid == 0){
      __builtin_amdgcn_fence(__ATOMIC_RELEASE, "workgroup");
      __hip_atomic_fetch_add(ctrA, 1u, __ATOMIC_RELAXED, __HIP_MEMORY_SCOPE_AGENT);
      unsigned tgt = 16u*(unsigned)(l+1);
      while (__hip_atomic_load(ctrA, __ATOMIC_RELAXED, __HIP_MEMORY_SCOPE_AGENT) < tgt)
        __builtin_amdgcn_s_sleep(1);
      __builtin_amdgcn_fence(__ATOMIC_ACQUIRE, "workgroup");
    }
    __syncthreads();
    if (tid < HD)
      nhF[tid] = __hip_atomic_load(&nhbuf[((size_t)(l&1)*B_ + b)*HD + tid],
                                   __ATOMIC_RELAXED, __HIP_MEMORY_SCOPE_AGENT);
    __syncthreads();
    // ---- scores over t-chunk (bf16 keys, conflict-free)
    {
      int t = tid & 127, dh = tid >> 7;
      const uint2* kp = &keyP[(dh*25)*129 + t];
      const float4* nf = (const float4*)nhF + dh*25;
      float s0 = 0.f, s1 = 0.f;
      #pragma unroll
      for (int q = 0; q < 25; ++q){
        uint2 kk = kp[(size_t)q*129];
        float4 nv = nf[q];
        s0 = fmaf(nv.x, __uint_as_float(kk.x << 16), s0);
        s1 = fmaf(nv.y, __uint_as_float(kk.x & 0xFFFF0000u), s1);
        s0 = fmaf(nv.z, __uint_as_float(kk.y << 16), s0);
        s1 = fmaf(nv.w, __uint_as_float(kk.y & 0xFFFF0000u), s1);
      }
      spL[tid] = s0 + s1;
    }
    __syncthreads();
    if (tid < 128){
      float s = spL[tid] + spL[tid + 128];
      float w = 0.f;
      if (t0 + tid < len){ s = fminf(60.f, fmaxf(-60.f, s)); w = __expf(s); }
      wL[tid] = w;
    } else if (tid < 178){
      int d = tid - 128;
      float a = 0.f;
      #pragma unroll
      for (int uu = 0; uu < 13; ++uu) a = fmaf(nhF[u0 + uu], Wa1s[uu*50 + d], a);
      apL[d] = a;
    }
    __syncthreads();
    if (tid >= 192){
      float v = wL[tid - 192] + wL[tid - 128];
      #pragma unroll
      for (int off = 32; off > 0; off >>= 1) v += __shfl_down(v, off);
      if (tid == 192) SL[0] = v;
    } else {
      int tc = tid >> 6, d = tid & 63;
      if (d < 50){
        int tlo = tc*43, thi = (tc == 2) ? 128 : tc*43 + 43;
        float a = 0.f;
        for (int t = tlo; t < thi; ++t) a = fmaf(wL[t], memAL[t*50 + d], a);
        cpL[tc*52 + d] = a;
      }
    }
    __syncthreads();
    // ---- publish partials (packed u64, relaxed agent atomics)
    {
      unsigned long long* pb = (unsigned long long*)partials + ((size_t)(b*16 + g))*64;
      if (tid < 25){
        float p0 = (cpL[2*tid]   + cpL[52 + 2*tid])   + cpL[104 + 2*tid];
        float p1 = (cpL[2*tid+1] + cpL[52 + 2*tid+1]) + cpL[104 + 2*tid+1];
        __hip_atomic_store(&pb[tid], pk2(p0, p1), __ATOMIC_RELAXED, __HIP_MEMORY_SCOPE_AGENT);
      } else if (tid < 50){
        int j = 2*(tid - 25);
        __hip_atomic_store(&pb[25 + (tid-25)], pk2(apL[j], apL[j+1]),
                           __ATOMIC_RELAXED, __HIP_MEMORY_SCOPE_AGENT);
      } else if (tid == 50){
        __hip_atomic_store(&pb[50], pk2(SL[0], 0.f),
                           __ATOMIC_RELAXED, __HIP_MEMORY_SCOPE_AGENT);
      }
    }
    __syncthreads();                       // drains vmcnt -> partials at IF
    // ---- barrier B arrive; zh(l+1)+dcx(l+1) hidden under the wait
    if (tid == 0){
      __builtin_amdgcn_fence(__ATOMIC_RELEASE, "workgroup");
      __hip_atomic_fetch_add(ctrB, 1u, __ATOMIC_RELAXED, __HIP_MEMORY_SCOPE_AGENT);
    }
    zh = 0.f;
    if (tid < 208){
      const float* Ub = &Uld[(50 + jc*50)*52 + o];
      const float* hp = &nhF[jc*50];
      #pragma unroll 10
      for (int j = 0; j < 50; ++j) zh = fmaf(hp[j], Ub[(size_t)j*52], zh);
      if (jc == 0 && l+1 < Lb)
        dcx = decx[((size_t)(b*L_ + (l+1)))*800 + (o&3)*200 + u0 + (o>>2)];
    }
    if (tid == 0){
      unsigned tgt = 16u*(unsigned)(l+1);
      while (__hip_atomic_load(ctrB, __ATOMIC_RELAXED, __HIP_MEMORY_SCOPE_AGENT) < tgt)
        __builtin_amdgcn_s_sleep(1);
      __builtin_amdgcn_fence(__ATOMIC_ACQUIRE, "workgroup");
    }
    __syncthreads();
    // ---- reduce partials -> attn (replicated; u64 relaxed agent loads)
    {
      const unsigned long long* pall = (const unsigned long long*)partials + ((size_t)b*16)*64;
      if (tid < 25){
        float c0 = 0.f, c1 = 0.f;
        #pragma unroll
        for (int gg = 0; gg < 16; ++gg){
          unsigned long long v = __hip_atomic_load(&pall[gg*64 + tid],
                                                   __ATOMIC_RELAXED, __HIP_MEMORY_SCOPE_AGENT);
          c0 += __uint_as_float((unsigned)v);
          c1 += __uint_as_float((unsigned)(v >> 32));
        }
        ctxR[2*tid] = c0; ctxR[2*tid+1] = c1;
      } else if (tid < 50){
        int j = tid - 25;
        float a0 = 0.f, a1 = 0.f;
        #pragma unroll
        for (int gg = 0; gg < 16; ++gg){
          unsigned long long v = __hip_atomic_load(&pall[gg*64 + 25 + j],
                                                   __ATOMIC_RELAXED, __HIP_MEMORY_SCOPE_AGENT);
          a0 += __uint_as_float((unsigned)v);
          a1 += __uint_as_float((unsigned)(v >> 32));
        }
        apR[2*j] = a0; apR[2*j+1] = a1;
      } else if (tid == 50){
        float Ss = 0.f;
        #pragma unroll
        for (int gg = 0; gg < 16; ++gg){
          unsigned long long v = __hip_atomic_load(&pall[gg*64 + 50],
                                                   __ATOMIC_RELAXED, __HIP_MEMORY_SCOPE_AGENT);
          Ss += __uint_as_float((unsigned)v);
        }
        SL[0] = Ss;
      }
    }
    __syncthreads();
    if (tid < 50) attnL[tid] = fmaf(ctxR[tid], rcp_(SL[0]), apR[tid]);
    __syncthreads();
  }
  // tail: out(Lb-1)
  if (g == 1 && tid < 6){
    float o_ = 0.f;
    for (int d = 0; d < AT; ++d) o_ = fmaf(attnL[d], WoutL[d*6 + tid], o_);
    out[((size_t)(b*L_ + (Lb-1)))*6 + tid] = o_;
  }
}

extern "C" void kernel_launch(void* const* d_in, const int* in_sizes, int n_in,
                              void* d_out, int out_size, void* d_ws, size_t ws_size,
                              hipStream_t stream)
{
  const float* signals   = (const float*)d_in[0];
  const float* embeddings= (const float*)d_in[1];
  const float* conv1_k   = (const float*)d_in[2];
  const float* conv1a_k  = (const float*)d_in[3];
  const float* conv1a_b  = (const float*)d_in[4];
  const float* conv2_k   = (const float*)d_in[5];
  const float* conv3_k   = (const float*)d_in[6];
  const float* W_fwd     = (const float*)d_in[7];
  const float* b_fwd     = (const float*)d_in[8];
  const float* W_bwd     = (const float*)d_in[9];
  const float* b_bwd     = (const float*)d_in[10];
  const float* W_dec     = (const float*)d_in[11];
  const float* b_dec     = (const float*)d_in[12];
  const float* W_mem     = (const float*)d_in[13];
  const float* W_attn    = (const float*)d_in[14];
  const float* W_out     = (const float*)d_in[15];
  const int*   labels    = (const int*)d_in[16];
  const int*   sig_len   = (const int*)d_in[17];
  const int*   base_len  = (const int*)d_in[18];
  float* out = (float*)d_out;
  char* ws = (char*)d_ws;

  const size_t o_E        = 0;
  const size_t o_c0h0     = 4096;
  const size_t o_nhbuf    = 32768;        // 2*16*200*4 = 25600
  const size_t o_partials = 65536;        // 256 groups * 64 u64 = 131072
  const size_t o_ctr      = 524288;       // 32 u32
  const size_t o_WpF      = 589824;       // 357*400*4 = 571200
  const size_t o_WpB      = 1161024;
  const size_t o_feat     = 4194304;      // feat 33.5MB; keys overlays
  const size_t o_mem      = o_feat + 33554432;   // memory 26.2MB
  const size_t o_X1       = o_mem + 26214400;    // 52.4MB xprojF / memA+decx overlay
  const size_t o_X2       = o_X1 + 52428800;     // xprojB when ws big enough

  bool bigws = (ws_size >= o_X2 + 52428800);

  float* E      = (float*)(ws + o_E);
  float* c0h0   = (float*)(ws + o_c0h0);
  float* nhbuf  = (float*)(ws + o_nhbuf);
  float* parts  = (float*)(ws + o_partials);
  unsigned int* ctrs = (unsigned int*)(ws + o_ctr);
  float* WpF    = (float*)(ws + o_WpF);
  float* WpB    = (float*)(ws + o_WpB);
  float* feat   = (float*)(ws + o_feat);
  float* keys   = feat;                          // overlay after encoder
  float* memory = (float*)(ws + o_mem);
  float* xprojF = (float*)(ws + o_X1);
  float* xprojB = bigws ? (float*)(ws + o_X2) : xprojF;
  float* memA   = (float*)(ws + o_X1);           // overlay after encoder
  float* decxA  = (float*)(ws + o_X1 + 6553600);
  float* decx   = (float*)(ws + o_X1 + 8650752);

  k_prep<<<1, 768, 0, stream>>>(conv1_k, conv1a_k, conv2_k, conv3_k, E);
  k_feat<<<8192, 256, 0, stream>>>(signals, E, conv1a_b, feat);
  k_permW<<<1116, 256, 0, stream>>>(W_fwd, b_fwd, W_bwd, b_bwd, WpF, WpB);

  dim3 gx(512, 7);
  if (bigws){
    k_gemm<<<gx, 256, 0, stream>>>(feat, WpF, WpF + 356*400, xprojF, 32768, 400, 256, 400);
    k_gemm<<<gx, 256, 0, stream>>>(feat, WpB, WpB + 356*400, xprojB, 32768, 400, 256, 400);
    k_encoder<<<32, 512, 0, stream>>>(xprojF, xprojB, WpF, WpB, sig_len, memory, c0h0, -1);
  } else {
    k_gemm<<<gx, 256, 0, stream>>>(feat, WpF, WpF + 356*400, xprojF, 32768, 400, 256, 400);
    k_encoder<<<16, 512, 0, stream>>>(xprojF, xprojF, WpF, WpB, sig_len, memory, c0h0, 0);
    k_gemm<<<gx, 256, 0, stream>>>(feat, WpB, WpB + 356*400, xprojF, 32768, 400, 256, 400);
    k_encoder<<<16, 512, 0, stream>>>(xprojF, xprojF, WpF, WpB, sig_len, memory, c0h0, 1);
  }

  k_gemm<<<dim3(512, 4), 256, 0, stream>>>(memory, W_mem, nullptr, keys, 32768, 200, 200, 200);
  k_gemm<<<dim3(512, 1), 256, 0, stream>>>(memory, W_attn + 200*50, nullptr, memA, 32768, 50, 200, 50);
  k_gather<<<2048, 256, 0, stream>>>(embeddings, labels, decxA);
  k_gemm<<<dim3(128, 13), 256, 0, stream>>>(decxA, W_dec, b_dec, decx, 8192, 800, 64, 800);
  k_dec_init<<<192, 256, 0, stream>>>(ctrs, out);

  hipFuncSetAttribute(reinterpret_cast<const void*>(k_decoder),
                      hipFuncAttributeMaxDynamicSharedMemorySize, DEC_LDS);
  k_decoder<<<256, 256, DEC_LDS, stream>>>(keys, memA, decx, W_dec, W_attn, W_out,
                                           c0h0, sig_len, base_len,
                                           nhbuf, parts, ctrs, out);
}

// Round 4
// 5631.296 us; speedup vs baseline: 2.5332x; 1.2235x over previous
//
#include <hip/hip_runtime.h>

#define B_ 16
#define T_ 2048
#define L_ 512
#define HD 200
#define AT 50

__device__ __forceinline__ float rcp_(float x){ return __builtin_amdgcn_rcpf(x); }
__device__ __forceinline__ float sigf(float x){ return rcp_(1.f + __expf(-x)); }
__device__ __forceinline__ float tanhf_(float x){
  x = fminf(15.f, fmaxf(-15.f, x));
  float e = __expf(-2.f*x);
  return (1.f - e) * rcp_(1.f + e);
}
__device__ __forceinline__ unsigned bf16u(float v){
  unsigned u = __float_as_uint(v);
  u += 0x7FFFu + ((u >> 16) & 1u);
  return u >> 16;
}
// pack (fp32 value, u32 seq) into one u64 -> atomically published datum+flag
__device__ __forceinline__ unsigned long long pkvs(float v, unsigned s){
  return (unsigned long long)__float_as_uint(v) | ((unsigned long long)s << 32);
}

// ---------------- conv fold: E[3][256] ----------------
__global__ void k_prep(const float* __restrict__ conv1, const float* __restrict__ conv1a,
                       const float* __restrict__ conv2, const float* __restrict__ conv3,
                       float* __restrict__ E)
{
  __shared__ float K2s[3*256];
  int tid = threadIdx.x;            // 768 threads
  int k = tid >> 8, co = tid & 255;
  float a = 0.f;
  for (int ci = 0; ci < 256; ++ci)
    a = fmaf(conv1[ci], conv2[(k*256 + ci)*256 + co], a);
  K2s[k*256 + co] = a;
  __syncthreads();
  float b2 = 0.f;
  for (int ci = 0; ci < 256; ++ci)
    b2 = fmaf(K2s[k*256 + ci], conv3[ci*256 + co], b2);
  if (k == 1) b2 += conv1a[co];
  E[k*256 + co] = b2;
}

// ---------------- feat[b,t,256] ----------------
__global__ void k_feat(const float* __restrict__ sig, const float* __restrict__ E,
                       const float* __restrict__ c1ab, float* __restrict__ feat)
{
  int idx = blockIdx.x*256 + threadIdx.x;   // grid 8192 -> 32768*64 float4
  int row = idx >> 6;
  int c4  = (idx & 63) * 4;
  int t = row & (T_-1);
  float sm = (t > 0)     ? sig[row-1] : 0.f;
  float s0 = sig[row];
  float sp = (t < T_-1)  ? sig[row+1] : 0.f;
  float4 e0 = *(const float4*)&E[0*256 + c4];
  float4 e1 = *(const float4*)&E[1*256 + c4];
  float4 e2 = *(const float4*)&E[2*256 + c4];
  float4 bb = *(const float4*)&c1ab[c4];
  float4 r;
  r.x = fmaxf(0.f, fmaf(sm, e0.x, fmaf(s0, e1.x, fmaf(sp, e2.x, bb.x))));
  r.y = fmaxf(0.f, fmaf(sm, e0.y, fmaf(s0, e1.y, fmaf(sp, e2.y, bb.y))));
  r.z = fmaxf(0.f, fmaf(sm, e0.z, fmaf(s0, e1.z, fmaf(sp, e2.z, bb.z))));
  r.w = fmaxf(0.f, fmaf(sm, e0.w, fmaf(s0, e1.w, fmaf(sp, e2.w, bb.w))));
  *(float4*)&feat[(size_t)row*256 + c4] = r;
}

// ---------------- generic fp32 GEMM: C[M,N] = A[M,K]*B[K,N] (+bias) ----------------
__global__ __launch_bounds__(256)
void k_gemm(const float* __restrict__ A, const float* __restrict__ B,
            const float* __restrict__ bias, float* __restrict__ C,
            int M, int N, int K, int ldb)
{
  __shared__ float As[16][65];
  __shared__ float Bs[16][65];
  int row0 = blockIdx.x*64, col0 = blockIdx.y*64;
  int tid = threadIdx.x;
  int tm = tid >> 4, tn = tid & 15;
  float acc[4][4] = {};
  for (int k0 = 0; k0 < K; k0 += 16){
    #pragma unroll
    for (int i = 0; i < 4; ++i){
      int e = tid + i*256;
      int m = e >> 4, kk = e & 15;
      float v = 0.f;
      if (k0 + kk < K) v = A[(size_t)(row0+m)*K + k0 + kk];
      As[kk][m] = v;
      int n = e & 63, kb = e >> 6;
      float w = 0.f;
      if (k0 + kb < K && col0 + n < N) w = B[(size_t)(k0+kb)*ldb + col0 + n];
      Bs[kb][n] = w;
    }
    __syncthreads();
    #pragma unroll
    for (int kk = 0; kk < 16; ++kk){
      float a[4], bv[4];
      #pragma unroll
      for (int i = 0; i < 4; ++i){ a[i] = As[kk][tm*4+i]; bv[i] = Bs[kk][tn*4+i]; }
      #pragma unroll
      for (int i = 0; i < 4; ++i)
        #pragma unroll
        for (int j = 0; j < 4; ++j)
          acc[i][j] = fmaf(a[i], bv[j], acc[i][j]);
    }
    __syncthreads();
  }
  #pragma unroll
  for (int i = 0; i < 4; ++i){
    int r = row0 + tm*4 + i;
    #pragma unroll
    for (int j = 0; j < 4; ++j){
      int cc = col0 + tn*4 + j;
      if (cc < N) C[(size_t)r*N + cc] = acc[i][j] + (bias ? bias[cc] : 0.f);
    }
  }
}

// ---------------- weight permute for quad-gate encoder layout ----------------
__global__ void k_permW(const float* __restrict__ Wf, const float* __restrict__ bf,
                        const float* __restrict__ Wb, const float* __restrict__ bb,
                        float* __restrict__ WpF, float* __restrict__ WpB)
{
  int idx = blockIdx.x*256 + threadIdx.x;
  if (idx >= 2*357*400) return;
  int w = idx / (357*400), r = idx - w*(357*400);
  int j = r / 400, col = r - j*400;
  int src = (col & 3)*100 + (col >> 2);
  const float* W = w ? Wb : Wf; const float* bs = w ? bb : bf;
  float v = (j < 356) ? W[j*400 + src] : bs[src];
  (w ? WpB : WpF)[j*400 + col] = v;
}

// ---------------- encoder: quad-gate, 1 barrier/step ----------------
__global__ __launch_bounds__(512, 1)
void k_encoder(const float* __restrict__ xprojF, const float* __restrict__ xprojB,
               const float* __restrict__ WpF, const float* __restrict__ WpB,
               const int* __restrict__ sig_len, float* __restrict__ memory,
               float* __restrict__ c0h0, int dirParam)
{
  int dir, b;
  if (dirParam < 0){ dir = blockIdx.x & 1; b = blockIdx.x >> 1; }
  else             { dir = dirParam;       b = blockIdx.x; }
  const float* xp = dir ? xprojB : xprojF;
  const float* Wp = dir ? WpB : WpF;
  int tid = threadIdx.x;
  int u = tid >> 2, gq = tid & 3;
  __shared__ __align__(16) float h2[2][104];
  float U[100];
  if (tid < 400){
    #pragma unroll
    for (int j = 0; j < 100; ++j) U[j] = Wp[(256 + j)*400 + tid];
  }
  if (tid < 100) h2[0][tid] = 0.f;
  int len = sig_len[b];
  float c = 0.f, hfin = 0.f;
  float xb0 = 0.f, xb1 = 0.f;
  if (tid < 400){
    int ta = dir ? (len-1) : 0;
    xb0 = xp[((size_t)(b*T_ + ta))*400 + tid];
    if (len > 1){
      int tb_ = dir ? (len-2) : 1;
      xb1 = xp[((size_t)(b*T_ + tb_))*400 + tid];
    }
  }
  for (int step = 0; step < len; ++step){
    __syncthreads();
    float z = xb0;
    float xn = 0.f;
    if (tid < 400){
      if (step + 2 < len){
        int tn = dir ? (len-3-step) : (step+2);
        xn = xp[((size_t)(b*T_ + tn))*400 + tid];
      }
      const float* hb = h2[step & 1];
      float a0 = z, a1 = 0.f, a2 = 0.f, a3 = 0.f;
      #pragma unroll
      for (int j4 = 0; j4 < 25; ++j4){
        float4 h4 = *(const float4*)&hb[j4*4];
        a0 = fmaf(h4.x, U[j4*4+0], a0);
        a1 = fmaf(h4.y, U[j4*4+1], a1);
        a2 = fmaf(h4.z, U[j4*4+2], a2);
        a3 = fmaf(h4.w, U[j4*4+3], a3);
      }
      z = (a0+a1)+(a2+a3);
    }
    float v0 = z, v1 = __shfl_xor(z, 1);
    float v2 = __shfl_xor(v0, 2), v3 = __shfl_xor(v1, 2);
    if (tid < 400){
      float tA  = (gq&1) ? v1 : v0, tB  = (gq&1) ? v3 : v2;
      float tA2 = (gq&1) ? v0 : v1, tB2 = (gq&1) ? v2 : v3;
      float zi = (gq&2) ? tB  : tA;
      float zj = (gq&2) ? tB2 : tA2;
      float zf = (gq&2) ? tA  : tB;
      float zo = (gq&2) ? tA2 : tB2;
      c = c*sigf(zf + 1.f) + sigf(zi)*tanhf_(zj);
      float nh = tanhf_(c)*sigf(zo);
      hfin = nh;
      if (gq == 0){
        int t = dir ? (len-1-step) : step;
        h2[(step+1)&1][u] = nh;
        memory[((size_t)(b*T_ + t))*200 + dir*100 + u] = nh;
      }
      xb0 = xb1; xb1 = xn;
    }
  }
  if (tid < 400 && gq == 0){
    c0h0[b*400 + dir*100 + u]       = c;
    c0h0[b*400 + 200 + dir*100 + u] = hfin;
  }
  int total = (T_ - len)*100;
  for (int i = tid; i < total; i += 512){
    int t = len + i/100;
    int k = i - (i/100)*100;
    memory[((size_t)(b*T_ + t))*200 + dir*100 + k] = 0.f;
  }
}

// ---------------- decoder input gather ----------------
__global__ void k_gather(const float* __restrict__ emb, const int* __restrict__ labels,
                         float* __restrict__ dA)
{
  int idx = blockIdx.x*256 + threadIdx.x;  // grid 2048
  int i = idx >> 6, e = idx & 63;
  dA[(size_t)i*64 + e] = emb[labels[i]*64 + e];
}

// ---------------- decoder init: zero out + seq slots ----------------
__global__ void k_dec_init(unsigned long long* __restrict__ nhb,
                           unsigned long long* __restrict__ parts,
                           float* __restrict__ out)
{
  int idx = blockIdx.x*256 + threadIdx.x;   // grid 192 -> 49152
  if (idx < B_*L_*6) out[idx] = 0.f;
  if (idx < B_*HD) nhb[idx] = 0ull;               // 3200
  if (idx < B_*16*112) parts[idx] = 0ull;         // 28672
}

// ---------------- cooperative decoder: 16 blocks per batch item ----------------
// Wait-free cross-block sync: every shared datum is a u64 (fp32 value, u32 seq)
// published via one relaxed agent-scope atomic store; consumers poll the datum
// itself until seq == l+1. No counters, no leader threads, no fences beyond
// per-access atomicity. One-deep overwrite races excluded by dataflow (a block
// can publish step l+1 only after consuming all of step l from every block).
#define DEC_LDS 137728
#define TCH 128

__global__ __launch_bounds__(256, 1)
void k_decoder(const float* __restrict__ keysG, const float* __restrict__ memAG,
               const float* __restrict__ decx,  const float* __restrict__ W_dec,
               const float* __restrict__ W_attn, const float* __restrict__ W_out,
               const float* __restrict__ c0h0, const int* __restrict__ sig_len,
               const int* __restrict__ base_len,
               unsigned long long* nhb, unsigned long long* partials,
               float* __restrict__ out)
{
  int blk = blockIdx.x;
  int b = (blk & 7) | (((blk >> 3) & 1) << 3);   // b's 16 blocks -> same XCD (blk%8 const)
  int g = blk >> 4;
  int tid = threadIdx.x;
  int u0 = g * 13;
  int nu = (HD - u0 < 13) ? (HD - u0) : 13;      // 13 (g<15) or 5 (g==15)
  int t0 = g * TCH;

  extern __shared__ char smem[];
  uint2* keyP  = (uint2*)(smem);                 // [p<50][t<128+pad] stride 129
  float* memAL = (float*)(smem + 51616);         // [128][50]
  float* Uld   = (float*)(smem + 77216);         // [250][52] rows: 0..49 attn, 50..249 h
  float* Wa1s  = (float*)(smem + 129216);        // [13][50]
  float* WoutL = (float*)(smem + 131824);        // [50][6]
  float* nhF   = (float*)(smem + 133024);        // [208] (16B aligned, tail zeroed)
  float* spL   = (float*)(smem + 133856);        // [256]
  float* wL    = (float*)(smem + 134880);        // [128]
  float* cpL   = (float*)(smem + 135392);        // [3][52]
  float* apL   = (float*)(smem + 136016);        // [52]
  float* zp    = (float*)(smem + 136224);        // [52][4]
  float* attnL = (float*)(smem + 137056);        // [52]
  float* SL    = (float*)(smem + 137264);        // [2]
  float* ctxR  = (float*)(smem + 137272);        // [52]
  float* apR   = (float*)(smem + 137480);        // [52]

  // ---- one-time fills (coalesced) ----
  for (int i = tid; i < TCH*50; i += 256){
    int t = i / 50, p = i - (i/50)*50;
    float4 kv = *(const float4*)&keysG[((size_t)(b*T_ + t0 + t))*200 + 4*p];
    keyP[p*129 + t] = make_uint2(bf16u(kv.x) | (bf16u(kv.y) << 16),
                                 bf16u(kv.z) | (bf16u(kv.w) << 16));
    memAL[t*50 + p] = memAG[((size_t)(b*T_ + t0 + t))*50 + p];
  }
  for (int i = tid; i < 250*52; i += 256){
    int j = i / 52, o_ = i - (i/52)*52;
    int uu = o_ >> 2, gg = o_ & 3;
    Uld[i] = (uu < nu) ? W_dec[(size_t)(64 + j)*800 + gg*200 + u0 + uu] : 0.f;
  }
  for (int i = tid; i < 13*50; i += 256){
    int uu = i / 50, d = i - (i/50)*50;
    Wa1s[i] = (uu < nu) ? W_attn[(size_t)(u0 + uu)*50 + d] : 0.f;
  }
  for (int i = tid; i < 300; i += 256) WoutL[i] = W_out[i];
  if (tid < 50) attnL[tid] = 0.f;
  if (tid < 8)  nhF[200 + tid] = 0.f;
  float creg = (tid < nu) ? c0h0[b*400 + u0 + tid] : 0.f;
  int len = sig_len[b];
  int Lb  = base_len[b];
  unsigned long long* nhB = nhb + (size_t)b*HD;
  __syncthreads();

  // ---- pre-loop: nhF = h0; zh(0); dcx(0) ----
  if (tid < 50) *(float4*)&nhF[tid*4] = *(const float4*)&c0h0[b*400 + 200 + tid*4];
  __syncthreads();
  int o  = tid - (tid/52)*52;
  int jc = tid / 52;
  float zh = 0.f, dcx = 0.f;
  if (tid < 208){
    const float* Ub = &Uld[(50 + jc*50)*52 + o];
    const float* hp = &nhF[jc*50];
    #pragma unroll 10
    for (int j = 0; j < 50; ++j) zh = fmaf(hp[j], Ub[(size_t)j*52], zh);
    if (jc == 0) dcx = decx[((size_t)(b*L_))*800 + (o&3)*200 + u0 + (o>>2)];
  }

  for (int l = 0; l < Lb; ++l){
    unsigned seq = (unsigned)(l + 1);
    // ---- A: za gemv (attn rows); g1 writes out(l-1)
    if (tid < 208){
      float z = zh + ((jc == 0) ? dcx : 0.f);
      const float* Ub = &Uld[(jc*13)*52 + o];
      const float* ap_ = &attnL[jc*13];
      int cnt = (jc < 3) ? 13 : 11;
      for (int j = 0; j < cnt; ++j) z = fmaf(ap_[j], Ub[(size_t)j*52], z);
      zp[o*4 + jc] = z;
    } else if (g == 1 && l > 0 && tid < 214){
      int j = tid - 208;
      float o_ = 0.f;
      for (int d = 0; d < AT; ++d) o_ = fmaf(attnL[d], WoutL[d*6 + j], o_);
      out[((size_t)(b*L_ + (l-1)))*6 + j] = o_;
    }
    __syncthreads();
    // ---- B: combine + activation; publish nh slice (u64 val+seq)
    if (tid < nu){
      const float* zz = &zp[(4*tid)*4];
      float zi = (zz[0]+zz[1])+(zz[2]+zz[3]);
      float zj = (zz[4]+zz[5])+(zz[6]+zz[7]);
      float zf = (zz[8]+zz[9])+(zz[10]+zz[11]);
      float zo = (zz[12]+zz[13])+(zz[14]+zz[15]);
      float c = creg;
      c = c*sigf(zf + 1.f) + sigf(zi)*tanhf_(zj);
      creg = c;
      float nh = tanhf_(c)*sigf(zo);
      __hip_atomic_store(&nhB[u0 + tid], pkvs(nh, seq),
                         __ATOMIC_RELAXED, __HIP_MEMORY_SCOPE_AGENT);
    }
    // ---- C: poll full nh vector (one slot per thread)
    if (tid < HD){
      unsigned long long v;
      do {
        v = __hip_atomic_load(&nhB[tid], __ATOMIC_RELAXED, __HIP_MEMORY_SCOPE_AGENT);
      } while ((unsigned)(v >> 32) != seq);
      nhF[tid] = __uint_as_float((unsigned)v);
    }
    __syncthreads();
    // ---- D: scores over t-chunk (bf16 keys, conflict-free)
    {
      int t = tid & 127, dh = tid >> 7;
      const uint2* kp = &keyP[(dh*25)*129 + t];
      const float4* nf = (const float4*)nhF + dh*25;
      float s0 = 0.f, s1 = 0.f;
      #pragma unroll
      for (int q = 0; q < 25; ++q){
        uint2 kk = kp[(size_t)q*129];
        float4 nv = nf[q];
        s0 = fmaf(nv.x, __uint_as_float(kk.x << 16), s0);
        s1 = fmaf(nv.y, __uint_as_float(kk.x & 0xFFFF0000u), s1);
        s0 = fmaf(nv.z, __uint_as_float(kk.y << 16), s0);
        s1 = fmaf(nv.w, __uint_as_float(kk.y & 0xFFFF0000u), s1);
      }
      spL[tid] = s0 + s1;
    }
    __syncthreads();
    // ---- E: w=exp ; ap gemv
    if (tid < 128){
      float s = spL[tid] + spL[tid + 128];
      float w = 0.f;
      if (t0 + tid < len){ s = fminf(60.f, fmaxf(-60.f, s)); w = __expf(s); }
      wL[tid] = w;
    } else if (tid < 178){
      int d = tid - 128;
      float a = 0.f;
      #pragma unroll
      for (int uu = 0; uu < 13; ++uu) a = fmaf(nhF[u0 + uu], Wa1s[uu*50 + d], a);
      apL[d] = a;
    }
    __syncthreads();
    // ---- F: ctx partials + S reduce
    if (tid >= 192){
      float v = wL[tid - 192] + wL[tid - 128];
      #pragma unroll
      for (int off = 32; off > 0; off >>= 1) v += __shfl_down(v, off);
      if (tid == 192) SL[0] = v;
    } else {
      int tc = tid >> 6, d = tid & 63;
      if (d < 50){
        int tlo = tc*43, thi = (tc == 2) ? 128 : tc*43 + 43;
        float a = 0.f;
        for (int t = tlo; t < thi; ++t) a = fmaf(wL[t], memAL[t*50 + d], a);
        cpL[tc*52 + d] = a;
      }
    }
    __syncthreads();
    // ---- G: publish partials; zh(l+1)+dcx(l+1); poll-reduce partials
    {
      unsigned long long* pb = partials + (size_t)(b*16 + g)*112;
      if (tid < 50)
        __hip_atomic_store(&pb[tid],
                           pkvs((cpL[tid] + cpL[52 + tid]) + cpL[104 + tid], seq),
                           __ATOMIC_RELAXED, __HIP_MEMORY_SCOPE_AGENT);
      else if (tid < 100)
        __hip_atomic_store(&pb[tid], pkvs(apL[tid - 50], seq),
                           __ATOMIC_RELAXED, __HIP_MEMORY_SCOPE_AGENT);
      else if (tid == 100)
        __hip_atomic_store(&pb[100], pkvs(SL[0], seq),
                           __ATOMIC_RELAXED, __HIP_MEMORY_SCOPE_AGENT);
    }
    zh = 0.f;
    if (tid < 208){
      const float* Ub = &Uld[(50 + jc*50)*52 + o];
      const float* hp = &nhF[jc*50];
      #pragma unroll 10
      for (int j = 0; j < 50; ++j) zh = fmaf(hp[j], Ub[(size_t)j*52], zh);
      if (jc == 0 && l+1 < Lb)
        dcx = decx[((size_t)(b*L_ + (l+1)))*800 + (o&3)*200 + u0 + (o>>2)];
    }
    if (tid < 101){
      const unsigned long long* base = partials + (size_t)b*16*112 + tid;
      unsigned long long v[16];
      #pragma unroll
      for (int gg = 0; gg < 16; ++gg)
        v[gg] = __hip_atomic_load(&base[gg*112], __ATOMIC_RELAXED, __HIP_MEMORY_SCOPE_AGENT);
      #pragma unroll
      for (int gg = 0; gg < 16; ++gg)
        while ((unsigned)(v[gg] >> 32) != seq)
          v[gg] = __hip_atomic_load(&base[gg*112], __ATOMIC_RELAXED, __HIP_MEMORY_SCOPE_AGENT);
      float acc = 0.f;
      #pragma unroll
      for (int gg = 0; gg < 16; ++gg) acc += __uint_as_float((unsigned)v[gg]);
      if (tid < 50) ctxR[tid] = acc;
      else if (tid < 100) apR[tid - 50] = acc;
      else SL[1] = acc;
    }
    __syncthreads();
    // ---- H: attn(l)
    if (tid < 50) attnL[tid] = fmaf(ctxR[tid], rcp_(SL[1]), apR[tid]);
    __syncthreads();
  }
  // tail: out(Lb-1)
  if (g == 1 && tid < 6){
    float o_ = 0.f;
    for (int d = 0; d < AT; ++d) o_ = fmaf(attnL[d], WoutL[d*6 + tid], o_);
    out[((size_t)(b*L_ + (Lb-1)))*6 + tid] = o_;
  }
}

extern "C" void kernel_launch(void* const* d_in, const int* in_sizes, int n_in,
                              void* d_out, int out_size, void* d_ws, size_t ws_size,
                              hipStream_t stream)
{
  const float* signals   = (const float*)d_in[0];
  const float* embeddings= (const float*)d_in[1];
  const float* conv1_k   = (const float*)d_in[2];
  const float* conv1a_k  = (const float*)d_in[3];
  const float* conv1a_b  = (const float*)d_in[4];
  const float* conv2_k   = (const float*)d_in[5];
  const float* conv3_k   = (const float*)d_in[6];
  const float* W_fwd     = (const float*)d_in[7];
  const float* b_fwd     = (const float*)d_in[8];
  const float* W_bwd     = (const float*)d_in[9];
  const float* b_bwd     = (const float*)d_in[10];
  const float* W_dec     = (const float*)d_in[11];
  const float* b_dec     = (const float*)d_in[12];
  const float* W_mem     = (const float*)d_in[13];
  const float* W_attn    = (const float*)d_in[14];
  const float* W_out     = (const float*)d_in[15];
  const int*   labels    = (const int*)d_in[16];
  const int*   sig_len   = (const int*)d_in[17];
  const int*   base_len  = (const int*)d_in[18];
  float* out = (float*)d_out;
  char* ws = (char*)d_ws;

  const size_t o_E        = 0;
  const size_t o_c0h0     = 4096;
  const size_t o_nhbuf    = 32768;        // 16*200 u64 = 25600
  const size_t o_partials = 65536;        // 16*16*112 u64 = 229376 -> ends 294912
  const size_t o_WpF      = 589824;       // 357*400*4 = 571200
  const size_t o_WpB      = 1161024;
  const size_t o_feat     = 4194304;      // feat 33.5MB; keys overlays
  const size_t o_mem      = o_feat + 33554432;   // memory 26.2MB
  const size_t o_X1       = o_mem + 26214400;    // 52.4MB xprojF / memA+decx overlay
  const size_t o_X2       = o_X1 + 52428800;     // xprojB when ws big enough

  bool bigws = (ws_size >= o_X2 + 52428800);

  float* E      = (float*)(ws + o_E);
  float* c0h0   = (float*)(ws + o_c0h0);
  unsigned long long* nhbuf = (unsigned long long*)(ws + o_nhbuf);
  unsigned long long* parts = (unsigned long long*)(ws + o_partials);
  float* WpF    = (float*)(ws + o_WpF);
  float* WpB    = (float*)(ws + o_WpB);
  float* feat   = (float*)(ws + o_feat);
  float* keys   = feat;                          // overlay after encoder
  float* memory = (float*)(ws + o_mem);
  float* xprojF = (float*)(ws + o_X1);
  float* xprojB = bigws ? (float*)(ws + o_X2) : xprojF;
  float* memA   = (float*)(ws + o_X1);           // overlay after encoder
  float* decxA  = (float*)(ws + o_X1 + 6553600);
  float* decx   = (float*)(ws + o_X1 + 8650752);

  k_prep<<<1, 768, 0, stream>>>(conv1_k, conv1a_k, conv2_k, conv3_k, E);
  k_feat<<<8192, 256, 0, stream>>>(signals, E, conv1a_b, feat);
  k_permW<<<1116, 256, 0, stream>>>(W_fwd, b_fwd, W_bwd, b_bwd, WpF, WpB);

  dim3 gx(512, 7);
  if (bigws){
    k_gemm<<<gx, 256, 0, stream>>>(feat, WpF, WpF + 356*400, xprojF, 32768, 400, 256, 400);
    k_gemm<<<gx, 256, 0, stream>>>(feat, WpB, WpB + 356*400, xprojB, 32768, 400, 256, 400);
    k_encoder<<<32, 512, 0, stream>>>(xprojF, xprojB, WpF, WpB, sig_len, memory, c0h0, -1);
  } else {
    k_gemm<<<gx, 256, 0, stream>>>(feat, WpF, WpF + 356*400, xprojF, 32768, 400, 256, 400);
    k_encoder<<<16, 512, 0, stream>>>(xprojF, xprojF, WpF, WpB, sig_len, memory, c0h0, 0);
    k_gemm<<<gx, 256, 0, stream>>>(feat, WpB, WpB + 356*400, xprojF, 32768, 400, 256, 400);
    k_encoder<<<16, 512, 0, stream>>>(xprojF, xprojF, WpF, WpB, sig_len, memory, c0h0, 1);
  }

  k_gemm<<<dim3(512, 4), 256, 0, stream>>>(memory, W_mem, nullptr, keys, 32768, 200, 200, 200);
  k_gemm<<<dim3(512, 1), 256, 0, stream>>>(memory, W_attn + 200*50, nullptr, memA, 32768, 50, 200, 50);
  k_gather<<<2048, 256, 0, stream>>>(embeddings, labels, decxA);
  k_gemm<<<dim3(128, 13), 256, 0, stream>>>(decxA, W_dec, b_dec, decx, 8192, 800, 64, 800);
  k_dec_init<<<192, 256, 0, stream>>>(nhbuf, parts, out);

  hipFuncSetAttribute(reinterpret_cast<const void*>(k_decoder),
                      hipFuncAttributeMaxDynamicSharedMemorySize, DEC_LDS);
  k_decoder<<<256, 256, DEC_LDS, stream>>>(keys, memA, decx, W_dec, W_attn, W_out,
                                           c0h0, sig_len, base_len,
                                           nhbuf, parts, out);
}